// Round 1
// baseline (349.281 us; speedup 1.0000x reference)
//
#include <hip/hip_runtime.h>
#include <hip/hip_bf16.h>
#include <math.h>

// Problem constants (from reference): B=4, S=2048, E=512, H=8, DK=64
#define B_ 4
#define S_ 2048
#define E_ 512
#define H_ 8
#define DK_ 64

typedef __attribute__((ext_vector_type(8))) short short8;   // 8 bf16 (4 VGPRs)
typedef __attribute__((ext_vector_type(4))) float f32x4;    // MFMA C/D frag

using bf16 = __hip_bfloat16;

__device__ inline short8 ld8(const bf16* p) {
  return *reinterpret_cast<const short8*>(p);
}

// ---------------------------------------------------------------------------
// Kernel 1: g[b][h][s][d] = cos(x[b][s][h*64+d] + theta[d]) in bf16,
// plus transposed copy gT[b][h][d][s] (for PV B-operand contiguous loads).
// ---------------------------------------------------------------------------
__global__ __launch_bounds__(256) void prep_g_kernel(
    const float* __restrict__ x, const float* __restrict__ theta,
    bf16* __restrict__ g, bf16* __restrict__ gT) {
  int bh = blockIdx.y;
  int b = bh >> 3, h = bh & 7;
  int s0 = blockIdx.x * 64;
  __shared__ bf16 tile[64][68];  // [s][d], pad 68 -> transposed read is 2-way (free)
  int tid = threadIdx.x;
  const float* xp = x + ((size_t)(b * S_ + s0)) * E_ + h * DK_;
  bf16* gp = g + ((size_t)bh * S_ + s0) * DK_;
#pragma unroll
  for (int it = 0; it < 16; ++it) {
    int idx = it * 256 + tid;
    int sr = idx >> 6, dc = idx & 63;
    float val = cosf(xp[(size_t)sr * E_ + dc] + theta[dc]);
    bf16 bv = __float2bfloat16(val);
    gp[sr * DK_ + dc] = bv;
    tile[sr][dc] = bv;
  }
  __syncthreads();
  bf16* gTp = gT + ((size_t)bh * DK_) * S_ + s0;
#pragma unroll
  for (int it = 0; it < 16; ++it) {
    int idx = it * 256 + tid;
    int dr = idx >> 6, sc = idx & 63;
    gTp[(size_t)dr * S_ + sc] = tile[sc][dr];
  }
}

// ---------------------------------------------------------------------------
// Kernel 2: W (fp32) -> bf16
// ---------------------------------------------------------------------------
__global__ void prep_w_kernel(const float* __restrict__ W, bf16* __restrict__ wb) {
  int i = (blockIdx.x * 256 + threadIdx.x) * 4;
  float4 v = *reinterpret_cast<const float4*>(W + i);
  wb[i + 0] = __float2bfloat16(v.x);
  wb[i + 1] = __float2bfloat16(v.y);
  wb[i + 2] = __float2bfloat16(v.z);
  wb[i + 3] = __float2bfloat16(v.w);
}

// ---------------------------------------------------------------------------
// Kernel 3: flash attention. One wave per 16 query rows; 4 waves/block,
// waves fully independent (no __syncthreads). Q=K=V=g.
// MFMA 16x16x32 bf16. A-layout: A[m=lane&15][k=quad*8+j] (verified m120).
// C/D layout: row=quad*4+reg, col=lane&15 (verified m89/m91).
// Scores = Q.K^T: B-operand needs K[n][k] with the same lane mapping as A.
// PV: B-operand needs V[k][d] -> contiguous along s in gT.
// ---------------------------------------------------------------------------
__global__ __launch_bounds__(256) void attn_kernel(
    const bf16* __restrict__ g, const bf16* __restrict__ gT,
    bf16* __restrict__ ao) {
  int wave = threadIdx.x >> 6;
  int lane = threadIdx.x & 63;
  int col = lane & 15, quad = lane >> 4;
  int bh = blockIdx.y;
  int q0 = (blockIdx.x * 4 + wave) * 16;
  const bf16* gp = g + (size_t)bh * S_ * DK_;
  const bf16* gTp = gT + (size_t)bh * DK_ * S_;
  __shared__ bf16 lds[4][16][40];  // per-wave P-transpose buffer (pad 40)
  bf16* lp = &lds[wave][0][0];

  // Q fragments (A-layout), loaded once: Q[q0+col][quad*8+j (+32)]
  short8 qa0 = ld8(gp + (size_t)(q0 + col) * DK_ + quad * 8);
  short8 qa1 = ld8(gp + (size_t)(q0 + col) * DK_ + 32 + quad * 8);

  f32x4 o0{0.f, 0.f, 0.f, 0.f}, o1{0.f, 0.f, 0.f, 0.f};
  f32x4 o2{0.f, 0.f, 0.f, 0.f}, o3{0.f, 0.f, 0.f, 0.f};
  float m[4] = {-INFINITY, -INFINITY, -INFINITY, -INFINITY};
  float l[4] = {0.f, 0.f, 0.f, 0.f};

  for (int kk = 0; kk < S_; kk += 32) {
    // K fragments (B-operand of QK^T): K[kk+grp*16+col][quad*8+j (+32)]
    short8 k00 = ld8(gp + (size_t)(kk + col) * DK_ + quad * 8);
    short8 k01 = ld8(gp + (size_t)(kk + col) * DK_ + 32 + quad * 8);
    short8 k10 = ld8(gp + (size_t)(kk + 16 + col) * DK_ + quad * 8);
    short8 k11 = ld8(gp + (size_t)(kk + 16 + col) * DK_ + 32 + quad * 8);
    f32x4 s0{0.f, 0.f, 0.f, 0.f}, s1{0.f, 0.f, 0.f, 0.f};
    s0 = __builtin_amdgcn_mfma_f32_16x16x32_bf16(qa0, k00, s0, 0, 0, 0);
    s0 = __builtin_amdgcn_mfma_f32_16x16x32_bf16(qa1, k01, s0, 0, 0, 0);
    s1 = __builtin_amdgcn_mfma_f32_16x16x32_bf16(qa0, k10, s1, 0, 0, 0);
    s1 = __builtin_amdgcn_mfma_f32_16x16x32_bf16(qa1, k11, s1, 0, 0, 0);

    // Online softmax. C-layout: this lane's reg r is row quad*4+r, col (keys).
    float p0[4], p1[4], al[4];
#pragma unroll
    for (int r = 0; r < 4; ++r) {
      float a = s0[r] * 0.125f;   // 1/sqrt(64)
      float c = s1[r] * 0.125f;
      float mx = fmaxf(a, c);
      mx = fmaxf(mx, __shfl_xor(mx, 1));
      mx = fmaxf(mx, __shfl_xor(mx, 2));
      mx = fmaxf(mx, __shfl_xor(mx, 4));
      mx = fmaxf(mx, __shfl_xor(mx, 8));   // row-max over 16 lanes of the quad
      float mn = fmaxf(m[r], mx);
      float a_ = __expf(m[r] - mn);        // -inf-init -> exp(-inf)=0, safe
      p0[r] = __expf(a - mn);
      p1[r] = __expf(c - mn);
      float rs = p0[r] + p1[r];
      rs += __shfl_xor(rs, 1);
      rs += __shfl_xor(rs, 2);
      rs += __shfl_xor(rs, 4);
      rs += __shfl_xor(rs, 8);
      l[r] = l[r] * a_ + rs;
      m[r] = mn;
      al[r] = a_;
    }
#pragma unroll
    for (int r = 0; r < 4; ++r) {
      o0[r] *= al[r]; o1[r] *= al[r]; o2[r] *= al[r]; o3[r] *= al[r];
    }

    // P: C-layout -> A-layout via per-wave LDS round trip (DS pipe in-order
    // within a wave; wave_barrier pins compiler ordering).
    __builtin_amdgcn_wave_barrier();
#pragma unroll
    for (int r = 0; r < 4; ++r) {
      int row = quad * 4 + r;
      lp[row * 40 + col] = __float2bfloat16(p0[r]);
      lp[row * 40 + 16 + col] = __float2bfloat16(p1[r]);
    }
    __builtin_amdgcn_wave_barrier();
    short8 pa = ld8(lp + col * 40 + quad * 8);  // A[m=col][k=quad*8+j], 16B aligned

    // PV: B-operand V[k=kk+quad*8+j][d=f*16+col] from gT (contiguous along s)
#pragma unroll
    for (int f = 0; f < 4; ++f) {
      short8 vf = ld8(gTp + (size_t)(f * 16 + col) * S_ + kk + quad * 8);
      f32x4& o = (f == 0 ? o0 : f == 1 ? o1 : f == 2 ? o2 : o3);
      o = __builtin_amdgcn_mfma_f32_16x16x32_bf16(pa, vf, o, 0, 0, 0);
    }
  }

  // Epilogue: normalize by l, store bf16 attnout in [b][s][e] layout
  int b = bh >> 3, h = bh & 7;
#pragma unroll
  for (int r = 0; r < 4; ++r) {
    float inv = 1.0f / l[r];
    int row = q0 + quad * 4 + r;
    bf16* op = ao + ((size_t)b * S_ + row) * E_ + h * DK_;
    op[col]      = __float2bfloat16(o0[r] * inv);
    op[16 + col] = __float2bfloat16(o1[r] * inv);
    op[32 + col] = __float2bfloat16(o2[r] * inv);
    op[48 + col] = __float2bfloat16(o3[r] * inv);
  }
}

// ---------------------------------------------------------------------------
// Kernel 4: out = attnout @ W^T + b   (M=8192, N=512, K=512), fp32 out.
// W[n][k] is contiguous along k -> B-operand loads identical to A (B^T pattern).
// ---------------------------------------------------------------------------
__global__ __launch_bounds__(256) void proj_kernel(
    const bf16* __restrict__ ao, const bf16* __restrict__ wb,
    const float* __restrict__ bias, float* __restrict__ out) {
  int wave = threadIdx.x >> 6, lane = threadIdx.x & 63;
  int col = lane & 15, quad = lane >> 4;
  int m0 = blockIdx.x * 64 + wave * 16;
  int n0 = blockIdx.y * 64;
  f32x4 acc[4] = {{0.f,0.f,0.f,0.f},{0.f,0.f,0.f,0.f},{0.f,0.f,0.f,0.f},{0.f,0.f,0.f,0.f}};
  for (int k0 = 0; k0 < E_; k0 += 32) {
    short8 a = ld8(ao + (size_t)(m0 + col) * E_ + k0 + quad * 8);
#pragma unroll
    for (int f = 0; f < 4; ++f) {
      short8 bfr = ld8(wb + (size_t)(n0 + f * 16 + col) * E_ + k0 + quad * 8);
      acc[f] = __builtin_amdgcn_mfma_f32_16x16x32_bf16(a, bfr, acc[f], 0, 0, 0);
    }
  }
#pragma unroll
  for (int f = 0; f < 4; ++f) {
#pragma unroll
    for (int r = 0; r < 4; ++r) {
      int row = m0 + quad * 4 + r;
      int n = n0 + f * 16 + col;
      out[(size_t)row * E_ + n] = acc[f][r] + bias[n];
    }
  }
}

// ---------------------------------------------------------------------------
// ws layout (needs ~25.7 MB):
//   [0)              g   bf16 [B,H,S,DK]   8388608 B
//   [8388608)        gT  bf16 [B,H,DK,S]   8388608 B
//   [16777216)       ao  bf16 [B,S,E]      8388608 B
//   [25165824)       wb  bf16 [E,E]         524288 B
// ---------------------------------------------------------------------------
extern "C" void kernel_launch(void* const* d_in, const int* in_sizes, int n_in,
                              void* d_out, int out_size, void* d_ws, size_t ws_size,
                              hipStream_t stream) {
  const float* x = (const float*)d_in[0];
  const float* theta = (const float*)d_in[1];
  const float* W = (const float*)d_in[2];
  const float* bias = (const float*)d_in[3];
  float* out = (float*)d_out;
  char* ws = (char*)d_ws;
  const size_t gsz = (size_t)B_ * H_ * S_ * DK_ * sizeof(bf16);  // 8388608
  bf16* g = (bf16*)ws;
  bf16* gT = (bf16*)(ws + gsz);
  bf16* ao = (bf16*)(ws + 2 * gsz);
  bf16* wb = (bf16*)(ws + 3 * gsz);

  prep_g_kernel<<<dim3(S_ / 64, B_ * H_), 256, 0, stream>>>(x, theta, g, gT);
  prep_w_kernel<<<dim3((E_ * E_) / (256 * 4)), 256, 0, stream>>>(W, wb);
  attn_kernel<<<dim3(S_ / 64, B_ * H_), 256, 0, stream>>>(g, gT, ao);
  proj_kernel<<<dim3((B_ * S_) / 64, E_ / 64), 256, 0, stream>>>(ao, wb, bias, out);
}

// Round 2
// 341.660 us; speedup vs baseline: 1.0223x; 1.0223x over previous
//
#include <hip/hip_runtime.h>
#include <hip/hip_bf16.h>
#include <math.h>

// Problem constants (from reference): B=4, S=2048, E=512, H=8, DK=64
#define B_ 4
#define S_ 2048
#define E_ 512
#define H_ 8
#define DK_ 64

typedef __attribute__((ext_vector_type(8))) short short8;    // 8 bf16 (4 VGPRs)
typedef __attribute__((ext_vector_type(4))) short short4_t;  // 4 bf16 (8 B)
typedef __attribute__((ext_vector_type(4))) float f32x4;     // MFMA C/D frag

using bf16 = __hip_bfloat16;

__device__ inline short8 ld8(const bf16* p) {
  return *reinterpret_cast<const short8*>(p);
}

static __device__ inline short f2bs(float f) {
  __hip_bfloat16 h = __float2bfloat16(f);
  return __builtin_bit_cast(short, h);
}

// ---------------------------------------------------------------------------
// Kernel 1: g[b][h][s][d] = cos(x[b][s][h*64+d] + theta[d]) in bf16,
// plus transposed copy gT[b][h][d][s] (for PV B-operand contiguous loads).
// __cosf: v_cos-based fast path; x+theta is ~N(0,2), bf16 rounding dominates.
// ---------------------------------------------------------------------------
__global__ __launch_bounds__(256) void prep_g_kernel(
    const float* __restrict__ x, const float* __restrict__ theta,
    bf16* __restrict__ g, bf16* __restrict__ gT) {
  int bh = blockIdx.y;
  int b = bh >> 3, h = bh & 7;
  int s0 = blockIdx.x * 64;
  __shared__ bf16 tile[64][68];  // [s][d], pad 68 -> transposed read 2-way (free)
  int tid = threadIdx.x;
  const float* xp = x + ((size_t)(b * S_ + s0)) * E_ + h * DK_;
  bf16* gp = g + ((size_t)bh * S_ + s0) * DK_;
#pragma unroll
  for (int it = 0; it < 16; ++it) {
    int idx = it * 256 + tid;
    int sr = idx >> 6, dc = idx & 63;
    float val = __cosf(xp[(size_t)sr * E_ + dc] + theta[dc]);
    bf16 bv = __float2bfloat16(val);
    gp[sr * DK_ + dc] = bv;
    tile[sr][dc] = bv;
  }
  __syncthreads();
  bf16* gTp = gT + ((size_t)bh * DK_) * S_ + s0;
#pragma unroll
  for (int it = 0; it < 16; ++it) {
    int idx = it * 256 + tid;
    int dr = idx >> 6, sc = idx & 63;
    gTp[(size_t)dr * S_ + sc] = tile[sc][dr];
  }
}

// ---------------------------------------------------------------------------
// Kernel 2: W (fp32) -> bf16
// ---------------------------------------------------------------------------
__global__ void prep_w_kernel(const float* __restrict__ W, bf16* __restrict__ wb) {
  int i = (blockIdx.x * 256 + threadIdx.x) * 4;
  float4 v = *reinterpret_cast<const float4*>(W + i);
  wb[i + 0] = __float2bfloat16(v.x);
  wb[i + 1] = __float2bfloat16(v.y);
  wb[i + 2] = __float2bfloat16(v.z);
  wb[i + 3] = __float2bfloat16(v.w);
}

// ---------------------------------------------------------------------------
// Kernel 3: flash attention, NO running max.
// Scores = Q.K^T/8 with |entries|<=1, DK=64 => s in [-8,8] provably.
// p = exp2(s*0.125*log2e - 8*log2e) == softmax numerator with constant shift.
// => zero shuffles in the K-loop; one denominator reduction at the end.
//
// 64-key blocks. Key interleave: QK mfma kb's B-row n holds key n*4+kb, so a
// lane's 4 scores (fixed r, kb=0..3) are ADJACENT keys col*4..col*4+3
// -> packed 8B ds_write_b64 P-stores (4/iter instead of 16 b16 stores).
// XOR octet swizzle (octet ^ (row>>2)) for the P tile: stores stay
// conflict-minimal (row spans all 32 banks), A-frag b128 reads get the
// uniform-8 window distribution (== conflict-free stride-1 baseline).
// MFMA 16x16x32 bf16; layouts as verified in round 0 (kernel passed).
// ---------------------------------------------------------------------------
__global__ __launch_bounds__(256) void attn_kernel(
    const bf16* __restrict__ g, const bf16* __restrict__ gT,
    bf16* __restrict__ ao) {
  int wave = threadIdx.x >> 6;
  int lane = threadIdx.x & 63;
  int col = lane & 15, quad = lane >> 4;
  int bh = blockIdx.y;
  int q0 = (blockIdx.x * 4 + wave) * 16;
  const bf16* gp = g + (size_t)bh * S_ * DK_;
  const bf16* gTp = gT + (size_t)bh * DK_ * S_;
  __shared__ short lds[4][16 * 72];  // per-wave P buffer, row stride 72 elems
  short* lp = &lds[wave][0];

  // Q fragments (A-layout), loaded once: Q[q0+col][quad*8+j (+32)]
  short8 qa0 = ld8(gp + (size_t)(q0 + col) * DK_ + quad * 8);
  short8 qa1 = ld8(gp + (size_t)(q0 + col) * DK_ + 32 + quad * 8);

  f32x4 o[4] = {{0.f,0.f,0.f,0.f},{0.f,0.f,0.f,0.f},{0.f,0.f,0.f,0.f},{0.f,0.f,0.f,0.f}};
  float l[4] = {0.f, 0.f, 0.f, 0.f};

  const float C1 = 0.18033688011112042f;   // 0.125 * log2(e)
  const float C2 = -11.541560327111707f;   // -8 * log2(e)

  // P-store element offset within row (octet swizzled); row term added per r.
  const int sto = (((col >> 1) ^ quad) * 8) + (col & 1) * 4;
  // P-read base: row=col, octets quad (^ swizzle) and +4.
  const short* rdp = lp + col * 72 + ((quad ^ (col >> 2)) * 8);

  for (int kk = 0; kk < S_; kk += 64) {
    // QK^T: 4 mfmas, mfma kb covers keys kk + n*4 + kb (n = B-row = col)
    f32x4 s[4];
#pragma unroll
    for (int kb = 0; kb < 4; ++kb) {
      const bf16* kp = gp + (size_t)(kk + col * 4 + kb) * DK_;
      short8 k0 = ld8(kp + quad * 8);
      short8 k1 = ld8(kp + 32 + quad * 8);
      f32x4 z{0.f, 0.f, 0.f, 0.f};
      z = __builtin_amdgcn_mfma_f32_16x16x32_bf16(qa0, k0, z, 0, 0, 0);
      s[kb] = __builtin_amdgcn_mfma_f32_16x16x32_bf16(qa1, k1, z, 0, 0, 0);
    }

    // p = exp2(fma(s, C1, C2)); accumulate denominator. No shuffles.
    float p[4][4];
#pragma unroll
    for (int r = 0; r < 4; ++r) {
#pragma unroll
      for (int kb = 0; kb < 4; ++kb)
        p[r][kb] = __builtin_amdgcn_exp2f(__builtin_fmaf(s[kb][r], C1, C2));
      l[r] += (p[r][0] + p[r][1]) + (p[r][2] + p[r][3]);
    }

    // P (C-layout) -> LDS (packed b64, swizzled) -> A-layout fragments
    __builtin_amdgcn_wave_barrier();
#pragma unroll
    for (int r = 0; r < 4; ++r) {
      short4_t pk;
      pk.x = f2bs(p[r][0]); pk.y = f2bs(p[r][1]);
      pk.z = f2bs(p[r][2]); pk.w = f2bs(p[r][3]);
      *reinterpret_cast<short4_t*>(lp + (quad * 4 + r) * 72 + sto) = pk;
    }
    __builtin_amdgcn_wave_barrier();
    short8 pa0 = *reinterpret_cast<const short8*>(rdp);
    short8 pa1 = *reinterpret_cast<const short8*>(rdp + 32);

    // PV: B-operand V[k=key][n=d] from gT (contiguous along key)
#pragma unroll
    for (int f = 0; f < 4; ++f) {
      const bf16* vp = gTp + (size_t)(f * 16 + col) * S_ + kk;
      short8 v0 = ld8(vp + quad * 8);
      short8 v1 = ld8(vp + 32 + quad * 8);
      o[f] = __builtin_amdgcn_mfma_f32_16x16x32_bf16(pa0, v0, o[f], 0, 0, 0);
      o[f] = __builtin_amdgcn_mfma_f32_16x16x32_bf16(pa1, v1, o[f], 0, 0, 0);
    }
  }

  // Denominator: reduce over the 16 lanes sharing each row (one-time cost)
#pragma unroll
  for (int r = 0; r < 4; ++r) {
    float t = l[r];
    t += __shfl_xor(t, 1);
    t += __shfl_xor(t, 2);
    t += __shfl_xor(t, 4);
    t += __shfl_xor(t, 8);
    l[r] = t;
  }

  // Epilogue: normalize, store bf16 attnout in [b][s][e] layout
  int b = bh >> 3, h = bh & 7;
#pragma unroll
  for (int r = 0; r < 4; ++r) {
    float inv = __builtin_amdgcn_rcpf(l[r]);
    int row = q0 + quad * 4 + r;
    bf16* op = ao + ((size_t)b * S_ + row) * E_ + h * DK_;
    op[col]      = __float2bfloat16(o[0][r] * inv);
    op[16 + col] = __float2bfloat16(o[1][r] * inv);
    op[32 + col] = __float2bfloat16(o[2][r] * inv);
    op[48 + col] = __float2bfloat16(o[3][r] * inv);
  }
}

// ---------------------------------------------------------------------------
// Kernel 4: out = attnout @ W^T + b   (M=8192, N=512, K=512), fp32 out.
// ---------------------------------------------------------------------------
__global__ __launch_bounds__(256) void proj_kernel(
    const bf16* __restrict__ ao, const bf16* __restrict__ wb,
    const float* __restrict__ bias, float* __restrict__ out) {
  int wave = threadIdx.x >> 6, lane = threadIdx.x & 63;
  int col = lane & 15, quad = lane >> 4;
  int m0 = blockIdx.x * 64 + wave * 16;
  int n0 = blockIdx.y * 64;
  f32x4 acc[4] = {{0.f,0.f,0.f,0.f},{0.f,0.f,0.f,0.f},{0.f,0.f,0.f,0.f},{0.f,0.f,0.f,0.f}};
  for (int k0 = 0; k0 < E_; k0 += 32) {
    short8 a = ld8(ao + (size_t)(m0 + col) * E_ + k0 + quad * 8);
#pragma unroll
    for (int f = 0; f < 4; ++f) {
      short8 bfr = ld8(wb + (size_t)(n0 + f * 16 + col) * E_ + k0 + quad * 8);
      acc[f] = __builtin_amdgcn_mfma_f32_16x16x32_bf16(a, bfr, acc[f], 0, 0, 0);
    }
  }
#pragma unroll
  for (int f = 0; f < 4; ++f) {
#pragma unroll
    for (int r = 0; r < 4; ++r) {
      int row = m0 + quad * 4 + r;
      int n = n0 + f * 16 + col;
      out[(size_t)row * E_ + n] = acc[f][r] + bias[n];
    }
  }
}

// ---------------------------------------------------------------------------
// ws layout (~25.7 MB):
//   [0)        g   bf16 [B,H,S,DK]   8388608 B
//   [8388608)  gT  bf16 [B,H,DK,S]   8388608 B
//   [16777216) ao  bf16 [B,S,E]      8388608 B
//   [25165824) wb  bf16 [E,E]         524288 B
// ---------------------------------------------------------------------------
extern "C" void kernel_launch(void* const* d_in, const int* in_sizes, int n_in,
                              void* d_out, int out_size, void* d_ws, size_t ws_size,
                              hipStream_t stream) {
  const float* x = (const float*)d_in[0];
  const float* theta = (const float*)d_in[1];
  const float* W = (const float*)d_in[2];
  const float* bias = (const float*)d_in[3];
  float* out = (float*)d_out;
  char* ws = (char*)d_ws;
  const size_t gsz = (size_t)B_ * H_ * S_ * DK_ * sizeof(bf16);  // 8388608
  bf16* g = (bf16*)ws;
  bf16* gT = (bf16*)(ws + gsz);
  bf16* ao = (bf16*)(ws + 2 * gsz);
  bf16* wb = (bf16*)(ws + 3 * gsz);

  prep_g_kernel<<<dim3(S_ / 64, B_ * H_), 256, 0, stream>>>(x, theta, g, gT);
  prep_w_kernel<<<dim3((E_ * E_) / (256 * 4)), 256, 0, stream>>>(W, wb);
  attn_kernel<<<dim3(S_ / 64, B_ * H_), 256, 0, stream>>>(g, gT, ao);
  proj_kernel<<<dim3((B_ * S_) / 64, E_ / 64), 256, 0, stream>>>(ao, wb, bias, out);
}

// Round 3
// 166.259 us; speedup vs baseline: 2.1008x; 2.0550x over previous
//
#include <hip/hip_runtime.h>
#include <hip/hip_bf16.h>
#include <math.h>

// Problem constants (from reference): B=4, S=2048, E=512, H=8, DK=64
#define B_ 4
#define S_ 2048
#define E_ 512
#define H_ 8
#define DK_ 64

typedef __attribute__((ext_vector_type(8))) short short8;    // 8 bf16 (4 VGPRs)
typedef __attribute__((ext_vector_type(4))) short short4_t;  // 4 bf16 (8 B)
typedef __attribute__((ext_vector_type(4))) float f32x4;     // MFMA C/D frag

using bf16 = __hip_bfloat16;

__device__ inline short8 ld8(const bf16* p) {
  return *reinterpret_cast<const short8*>(p);
}

static __device__ inline short f2bs(float f) {
  __hip_bfloat16 h = __float2bfloat16(f);
  return __builtin_bit_cast(short, h);
}

// ---------------------------------------------------------------------------
// Kernel 1: g[b][h][s][d] = cos(x[b][s][h*64+d] + theta[d]) bf16,
// plus gT[b][h][d][s] for the PV B-operand / V-tile staging.
// ---------------------------------------------------------------------------
__global__ __launch_bounds__(256) void prep_g_kernel(
    const float* __restrict__ x, const float* __restrict__ theta,
    bf16* __restrict__ g, bf16* __restrict__ gT) {
  int bh = blockIdx.y;
  int b = bh >> 3, h = bh & 7;
  int s0 = blockIdx.x * 64;
  __shared__ bf16 tile[64][68];
  int tid = threadIdx.x;
  const float* xp = x + ((size_t)(b * S_ + s0)) * E_ + h * DK_;
  bf16* gp = g + ((size_t)bh * S_ + s0) * DK_;
#pragma unroll
  for (int it = 0; it < 16; ++it) {
    int idx = it * 256 + tid;
    int sr = idx >> 6, dc = idx & 63;
    float val = __cosf(xp[(size_t)sr * E_ + dc] + theta[dc]);
    bf16 bv = __float2bfloat16(val);
    gp[sr * DK_ + dc] = bv;
    tile[sr][dc] = bv;
  }
  __syncthreads();
  bf16* gTp = gT + ((size_t)bh * DK_) * S_ + s0;
#pragma unroll
  for (int it = 0; it < 16; ++it) {
    int idx = it * 256 + tid;
    int dr = idx >> 6, sc = idx & 63;
    gTp[(size_t)dr * S_ + sc] = tile[sc][dr];
  }
}

// ---------------------------------------------------------------------------
// Kernel 2: W (fp32) -> bf16
// ---------------------------------------------------------------------------
__global__ void prep_w_kernel(const float* __restrict__ W, bf16* __restrict__ wb) {
  int i = (blockIdx.x * 256 + threadIdx.x) * 4;
  float4 v = *reinterpret_cast<const float4*>(W + i);
  wb[i + 0] = __float2bfloat16(v.x);
  wb[i + 1] = __float2bfloat16(v.y);
  wb[i + 2] = __float2bfloat16(v.z);
  wb[i + 3] = __float2bfloat16(v.w);
}

// ---------------------------------------------------------------------------
// Kernel 3: flash attention, LDS-staged K/V tiles (fixes R2's L1-transaction
// fragmentation: the old per-lane 16B loads at 512B/4KB stride split into
// 16-64 transactions each; staging loads are fully coalesced).
//
// Block = 128 q rows; wave = 32 q rows (two 16-row A subtiles) -> B-operand
// LDS traffic amortized 2x, V-frags shared across subtiles.
// Tiles in LDS at row stride 72 shorts (144 B): fragment reads, staging
// writes, and P round-trip all spread exactly 8 words/bank (even = optimal).
// Constant-shift softmax (scores provably in [-8,8]), P transpose via
// per-wave swizzled LDS buffer (verified R2). Single buffer, 2 barriers/iter,
// next-tile register prefetch issued right after barrier 1.
// ---------------------------------------------------------------------------
__global__ __launch_bounds__(256) void attn_kernel(
    const bf16* __restrict__ g, const bf16* __restrict__ gT,
    bf16* __restrict__ ao) {
  const int tid = threadIdx.x;
  const int wave = tid >> 6, lane = tid & 63;
  const int col = lane & 15, quad = lane >> 4;
  const int bh = blockIdx.y;
  const int q0 = blockIdx.x * 128 + wave * 32;
  const bf16* gp = g + (size_t)bh * S_ * DK_;
  const bf16* gTp = gT + (size_t)bh * DK_ * S_;

  __shared__ short kt[64 * 72];     // K tile: row = local key, 64 d elems
  __shared__ short vt[64 * 72];     // V tile: row = d, 64 local-key elems
  __shared__ short pt[4][32 * 72];  // per-wave P buffer
  short* lp = &pt[wave][0];

  // Q frags (A-layout), loaded once per subtile t: rows q0+t*16+col
  short8 qa[2][2];
#pragma unroll
  for (int t = 0; t < 2; ++t) {
    const bf16* qp = gp + (size_t)(q0 + t * 16 + col) * DK_ + quad * 8;
    qa[t][0] = ld8(qp);
    qa[t][1] = ld8(qp + 32);
  }

  f32x4 o[2][4];
#pragma unroll
  for (int t = 0; t < 2; ++t)
#pragma unroll
    for (int f = 0; f < 4; ++f) o[t][f] = f32x4{0.f, 0.f, 0.f, 0.f};
  float l[2][4] = {{0.f, 0.f, 0.f, 0.f}, {0.f, 0.f, 0.f, 0.f}};

  const float C1 = 0.18033688011112042f;   // 0.125 * log2(e)
  const float C2 = -11.541560327111707f;   // -8 * log2(e)

  // P-transpose swizzle (verified R2), per 16-row subtile
  const int sto = (((col >> 1) ^ quad) * 8) + ((col & 1) * 4);
  const int rdo = (quad ^ (col >> 2)) * 8;

  // Staging: 512 16B-chunks per tile; thread handles chunks tid and tid+256.
  const int srow = tid >> 3;        // 0..31
  const int soct = (tid & 7) * 8;   // short offset within row
  short* kd0 = kt + srow * 72 + soct;
  short* kd1 = kt + (srow + 32) * 72 + soct;
  short* vd0 = vt + srow * 72 + soct;
  short* vd1 = vt + (srow + 32) * 72 + soct;
  const bf16* kg0 = gp + tid * 8;           // + kk*64
  const bf16* kg1 = gp + (tid + 256) * 8;
  const bf16* vg0 = gTp + (size_t)srow * S_ + (tid & 7) * 8;        // + kk
  const bf16* vg1 = gTp + (size_t)(srow + 32) * S_ + (tid & 7) * 8;

  short8 kr0 = ld8(kg0), kr1 = ld8(kg1), vr0 = ld8(vg0), vr1 = ld8(vg1);

  for (int kk = 0; kk < S_; kk += 64) {
    // Stage current tile from prefetch regs
    *reinterpret_cast<short8*>(kd0) = kr0;
    *reinterpret_cast<short8*>(kd1) = kr1;
    *reinterpret_cast<short8*>(vd0) = vr0;
    *reinterpret_cast<short8*>(vd1) = vr1;
    __syncthreads();

    // Prefetch next tile (overlaps with compute below)
    if (kk + 64 < S_) {
      kr0 = ld8(kg0 + (kk + 64) * 64);
      kr1 = ld8(kg1 + (kk + 64) * 64);
      vr0 = ld8(vg0 + kk + 64);
      vr1 = ld8(vg1 + kk + 64);
    }

    // QK^T: mfma kb covers local keys n*4+kb (n = B-row = col)
    f32x4 s[2][4];
#pragma unroll
    for (int kb = 0; kb < 4; ++kb) {
      const short* kr = kt + (col * 4 + kb) * 72 + quad * 8;
      short8 k0 = *reinterpret_cast<const short8*>(kr);
      short8 k1 = *reinterpret_cast<const short8*>(kr + 32);
#pragma unroll
      for (int t = 0; t < 2; ++t) {
        f32x4 z{0.f, 0.f, 0.f, 0.f};
        z = __builtin_amdgcn_mfma_f32_16x16x32_bf16(qa[t][0], k0, z, 0, 0, 0);
        s[t][kb] = __builtin_amdgcn_mfma_f32_16x16x32_bf16(qa[t][1], k1, z, 0, 0, 0);
      }
    }

    // Softmax numerators (constant shift, no shuffles) + packed P store
    __builtin_amdgcn_wave_barrier();
#pragma unroll
    for (int t = 0; t < 2; ++t) {
#pragma unroll
      for (int r = 0; r < 4; ++r) {
        float p0 = __builtin_amdgcn_exp2f(__builtin_fmaf(s[t][0][r], C1, C2));
        float p1 = __builtin_amdgcn_exp2f(__builtin_fmaf(s[t][1][r], C1, C2));
        float p2 = __builtin_amdgcn_exp2f(__builtin_fmaf(s[t][2][r], C1, C2));
        float p3 = __builtin_amdgcn_exp2f(__builtin_fmaf(s[t][3][r], C1, C2));
        l[t][r] += (p0 + p1) + (p2 + p3);
        short4_t pk;
        pk.x = f2bs(p0); pk.y = f2bs(p1); pk.z = f2bs(p2); pk.w = f2bs(p3);
        *reinterpret_cast<short4_t*>(lp + (t * 16 + quad * 4 + r) * 72 + sto) = pk;
      }
    }
    __builtin_amdgcn_wave_barrier();
    short8 pa[2][2];
#pragma unroll
    for (int t = 0; t < 2; ++t) {
      const short* rp = lp + (t * 16 + col) * 72 + rdo;
      pa[t][0] = *reinterpret_cast<const short8*>(rp);
      pa[t][1] = *reinterpret_cast<const short8*>(rp + 32);
    }

    // PV: V-frags read once, shared by both subtiles
#pragma unroll
    for (int f = 0; f < 4; ++f) {
      const short* vr = vt + (f * 16 + col) * 72 + quad * 8;
      short8 v0 = *reinterpret_cast<const short8*>(vr);
      short8 v1 = *reinterpret_cast<const short8*>(vr + 32);
      o[0][f] = __builtin_amdgcn_mfma_f32_16x16x32_bf16(pa[0][0], v0, o[0][f], 0, 0, 0);
      o[0][f] = __builtin_amdgcn_mfma_f32_16x16x32_bf16(pa[0][1], v1, o[0][f], 0, 0, 0);
      o[1][f] = __builtin_amdgcn_mfma_f32_16x16x32_bf16(pa[1][0], v0, o[1][f], 0, 0, 0);
      o[1][f] = __builtin_amdgcn_mfma_f32_16x16x32_bf16(pa[1][1], v1, o[1][f], 0, 0, 0);
    }
    __syncthreads();  // all reads done before next iter overwrites tiles
  }

  // Denominator reduction (one-time) + normalize + store
  int b = bh >> 3, h = bh & 7;
#pragma unroll
  for (int t = 0; t < 2; ++t) {
#pragma unroll
    for (int r = 0; r < 4; ++r) {
      float tt = l[t][r];
      tt += __shfl_xor(tt, 1);
      tt += __shfl_xor(tt, 2);
      tt += __shfl_xor(tt, 4);
      tt += __shfl_xor(tt, 8);
      float inv = __builtin_amdgcn_rcpf(tt);
      int row = q0 + t * 16 + quad * 4 + r;
      bf16* op = ao + ((size_t)b * S_ + row) * E_ + h * DK_;
      op[col]      = __float2bfloat16(o[t][0][r] * inv);
      op[16 + col] = __float2bfloat16(o[t][1][r] * inv);
      op[32 + col] = __float2bfloat16(o[t][2][r] * inv);
      op[48 + col] = __float2bfloat16(o[t][3][r] * inv);
    }
  }
}

// ---------------------------------------------------------------------------
// Kernel 4: out = attnout @ W^T + b   (M=8192, N=512, K=512), fp32 out.
// ---------------------------------------------------------------------------
__global__ __launch_bounds__(256) void proj_kernel(
    const bf16* __restrict__ ao, const bf16* __restrict__ wb,
    const float* __restrict__ bias, float* __restrict__ out) {
  int wave = threadIdx.x >> 6, lane = threadIdx.x & 63;
  int col = lane & 15, quad = lane >> 4;
  int m0 = blockIdx.x * 64 + wave * 16;
  int n0 = blockIdx.y * 64;
  f32x4 acc[4] = {{0.f,0.f,0.f,0.f},{0.f,0.f,0.f,0.f},{0.f,0.f,0.f,0.f},{0.f,0.f,0.f,0.f}};
  for (int k0 = 0; k0 < E_; k0 += 32) {
    short8 a = ld8(ao + (size_t)(m0 + col) * E_ + k0 + quad * 8);
#pragma unroll
    for (int f = 0; f < 4; ++f) {
      short8 bfr = ld8(wb + (size_t)(n0 + f * 16 + col) * E_ + k0 + quad * 8);
      acc[f] = __builtin_amdgcn_mfma_f32_16x16x32_bf16(a, bfr, acc[f], 0, 0, 0);
    }
  }
#pragma unroll
  for (int f = 0; f < 4; ++f) {
#pragma unroll
    for (int r = 0; r < 4; ++r) {
      int row = m0 + quad * 4 + r;
      int n = n0 + f * 16 + col;
      out[(size_t)row * E_ + n] = acc[f][r] + bias[n];
    }
  }
}

// ---------------------------------------------------------------------------
// ws layout (~25.7 MB):
//   [0)        g   bf16 [B,H,S,DK]   8388608 B
//   [8388608)  gT  bf16 [B,H,DK,S]   8388608 B
//   [16777216) ao  bf16 [B,S,E]      8388608 B
//   [25165824) wb  bf16 [E,E]         524288 B
// ---------------------------------------------------------------------------
extern "C" void kernel_launch(void* const* d_in, const int* in_sizes, int n_in,
                              void* d_out, int out_size, void* d_ws, size_t ws_size,
                              hipStream_t stream) {
  const float* x = (const float*)d_in[0];
  const float* theta = (const float*)d_in[1];
  const float* W = (const float*)d_in[2];
  const float* bias = (const float*)d_in[3];
  float* out = (float*)d_out;
  char* ws = (char*)d_ws;
  const size_t gsz = (size_t)B_ * H_ * S_ * DK_ * sizeof(bf16);  // 8388608
  bf16* g = (bf16*)ws;
  bf16* gT = (bf16*)(ws + gsz);
  bf16* ao = (bf16*)(ws + 2 * gsz);
  bf16* wb = (bf16*)(ws + 3 * gsz);

  prep_g_kernel<<<dim3(S_ / 64, B_ * H_), 256, 0, stream>>>(x, theta, g, gT);
  prep_w_kernel<<<dim3((E_ * E_) / (256 * 4)), 256, 0, stream>>>(W, wb);
  attn_kernel<<<dim3(S_ / 128, B_ * H_), 256, 0, stream>>>(g, gT, ao);
  proj_kernel<<<dim3((B_ * S_) / 64, E_ / 64), 256, 0, stream>>>(ao, wb, bias, out);
}

// Round 5
// 141.663 us; speedup vs baseline: 2.4656x; 1.1736x over previous
//
#include <hip/hip_runtime.h>
#include <hip/hip_bf16.h>
#include <math.h>

// Problem constants (from reference): B=4, S=2048, E=512, H=8, DK=64
#define B_ 4
#define S_ 2048
#define E_ 512
#define H_ 8
#define DK_ 64

typedef __attribute__((ext_vector_type(8))) short short8;    // 8 bf16 (4 VGPRs)
typedef __attribute__((ext_vector_type(4))) float f32x4;     // MFMA C/D frag

using bf16 = __hip_bfloat16;

__device__ inline short8 ld8(const bf16* p) {
  return *reinterpret_cast<const short8*>(p);
}

static __device__ inline unsigned short f2bs(float f) {
  __hip_bfloat16 h = __float2bfloat16(f);
  return (unsigned short)__builtin_bit_cast(short, h);
}

// pack two bf16 converts into one u32 (lo=a, hi=b)
static __device__ inline unsigned f2bs2(float a, float b) {
  return (unsigned)f2bs(a) | ((unsigned)f2bs(b) << 16);
}

// ---------------------------------------------------------------------------
// Kernel 1: g[b][h][s][d] = cos(x[b][s][h*64+d] + theta[d]) bf16,
// plus gT[b][h][d][s] for V-tile staging.
// ---------------------------------------------------------------------------
__global__ __launch_bounds__(256) void prep_g_kernel(
    const float* __restrict__ x, const float* __restrict__ theta,
    bf16* __restrict__ g, bf16* __restrict__ gT) {
  int bh = blockIdx.y;
  int b = bh >> 3, h = bh & 7;
  int s0 = blockIdx.x * 64;
  __shared__ bf16 tile[64][68];
  int tid = threadIdx.x;
  const float* xp = x + ((size_t)(b * S_ + s0)) * E_ + h * DK_;
  bf16* gp = g + ((size_t)bh * S_ + s0) * DK_;
#pragma unroll
  for (int it = 0; it < 16; ++it) {
    int idx = it * 256 + tid;
    int sr = idx >> 6, dc = idx & 63;
    float val = __cosf(xp[(size_t)sr * E_ + dc] + theta[dc]);
    bf16 bv = __float2bfloat16(val);
    gp[sr * DK_ + dc] = bv;
    tile[sr][dc] = bv;
  }
  __syncthreads();
  bf16* gTp = gT + ((size_t)bh * DK_) * S_ + s0;
#pragma unroll
  for (int it = 0; it < 16; ++it) {
    int idx = it * 256 + tid;
    int dr = idx >> 6, sc = idx & 63;
    gTp[(size_t)dr * S_ + sc] = tile[sc][dr];
  }
}

// ---------------------------------------------------------------------------
// Kernel 2: W (fp32) -> bf16
// ---------------------------------------------------------------------------
__global__ void prep_w_kernel(const float* __restrict__ W, bf16* __restrict__ wb) {
  int i = (blockIdx.x * 256 + threadIdx.x) * 4;
  float4 v = *reinterpret_cast<const float4*>(W + i);
  wb[i + 0] = __float2bfloat16(v.x);
  wb[i + 1] = __float2bfloat16(v.y);
  wb[i + 2] = __float2bfloat16(v.z);
  wb[i + 3] = __float2bfloat16(v.w);
}

// ---------------------------------------------------------------------------
// Kernel 3: flash attention. R3 structure (LDS-staged K/V, constant-shift
// softmax, swizzled P round-trip) + K/V DOUBLE-BUFFER: one __syncthreads per
// iter. Iter i reads buf i&1; tail of iter i writes buf (i+1)&1; the barrier
// at the head of iter i+1 fences those writes against iter i+1's reads.
// ---------------------------------------------------------------------------
__global__ __launch_bounds__(256) void attn_kernel(
    const bf16* __restrict__ g, const bf16* __restrict__ gT,
    bf16* __restrict__ ao) {
  const int tid = threadIdx.x;
  const int wave = tid >> 6, lane = tid & 63;
  const int col = lane & 15, quad = lane >> 4;
  const int bh = blockIdx.y;
  const int q0 = blockIdx.x * 128 + wave * 32;
  const bf16* gp = g + (size_t)bh * S_ * DK_;
  const bf16* gTp = gT + (size_t)bh * DK_ * S_;

  __shared__ short kt[2][64 * 72];   // K tiles: row = local key
  __shared__ short vt[2][64 * 72];   // V tiles: row = d
  __shared__ short pt[4][32 * 72];   // per-wave P buffer
  short* lp = &pt[wave][0];

  short8 qa[2][2];
#pragma unroll
  for (int t = 0; t < 2; ++t) {
    const bf16* qp = gp + (size_t)(q0 + t * 16 + col) * DK_ + quad * 8;
    qa[t][0] = ld8(qp);
    qa[t][1] = ld8(qp + 32);
  }

  f32x4 o[2][4];
#pragma unroll
  for (int t = 0; t < 2; ++t)
#pragma unroll
    for (int f = 0; f < 4; ++f) o[t][f] = f32x4{0.f, 0.f, 0.f, 0.f};
  float l[2][4] = {{0.f, 0.f, 0.f, 0.f}, {0.f, 0.f, 0.f, 0.f}};

  const float C1 = 0.18033688011112042f;   // 0.125 * log2(e)
  const float C2 = -11.541560327111707f;   // -8 * log2(e)

  const int sto = (((col >> 1) ^ quad) * 8) + ((col & 1) * 4);
  const int rdo = (quad ^ (col >> 2)) * 8;

  // Staging: 512 16B-chunks per tile; thread handles chunks tid and tid+256.
  const int srow = tid >> 3;
  const int soct = (tid & 7) * 8;
  const int sd0 = srow * 72 + soct;
  const int sd1 = (srow + 32) * 72 + soct;
  const bf16* kg0 = gp + tid * 8;
  const bf16* kg1 = gp + (tid + 256) * 8;
  const bf16* vg0 = gTp + (size_t)srow * S_ + (tid & 7) * 8;
  const bf16* vg1 = gTp + (size_t)(srow + 32) * S_ + (tid & 7) * 8;

  short8 kr0 = ld8(kg0), kr1 = ld8(kg1), vr0 = ld8(vg0), vr1 = ld8(vg1);

  for (int kk = 0; kk < S_; kk += 64) {
    const int buf = (kk >> 6) & 1;
    short* kb_ = &kt[buf][0];
    short* vb_ = &vt[buf][0];
    // Stage current tile from prefetch regs
    *reinterpret_cast<short8*>(kb_ + sd0) = kr0;
    *reinterpret_cast<short8*>(kb_ + sd1) = kr1;
    *reinterpret_cast<short8*>(vb_ + sd0) = vr0;
    *reinterpret_cast<short8*>(vb_ + sd1) = vr1;
    __syncthreads();

    // Prefetch next tile (lands in regs; written to buf^1 at next iter head)
    if (kk + 64 < S_) {
      kr0 = ld8(kg0 + (kk + 64) * 64);
      kr1 = ld8(kg1 + (kk + 64) * 64);
      vr0 = ld8(vg0 + kk + 64);
      vr1 = ld8(vg1 + kk + 64);
    }

    // QK^T: mfma kb covers local keys n*4+kb (n = B-row = col)
    f32x4 s[2][4];
#pragma unroll
    for (int kb = 0; kb < 4; ++kb) {
      const short* kr = kb_ + (col * 4 + kb) * 72 + quad * 8;
      short8 k0 = *reinterpret_cast<const short8*>(kr);
      short8 k1 = *reinterpret_cast<const short8*>(kr + 32);
#pragma unroll
      for (int t = 0; t < 2; ++t) {
        f32x4 z{0.f, 0.f, 0.f, 0.f};
        z = __builtin_amdgcn_mfma_f32_16x16x32_bf16(qa[t][0], k0, z, 0, 0, 0);
        s[t][kb] = __builtin_amdgcn_mfma_f32_16x16x32_bf16(qa[t][1], k1, z, 0, 0, 0);
      }
    }

    // Softmax numerators (constant shift) + packed P store
    __builtin_amdgcn_wave_barrier();
#pragma unroll
    for (int t = 0; t < 2; ++t) {
#pragma unroll
      for (int r = 0; r < 4; ++r) {
        float p0 = __builtin_amdgcn_exp2f(__builtin_fmaf(s[t][0][r], C1, C2));
        float p1 = __builtin_amdgcn_exp2f(__builtin_fmaf(s[t][1][r], C1, C2));
        float p2 = __builtin_amdgcn_exp2f(__builtin_fmaf(s[t][2][r], C1, C2));
        float p3 = __builtin_amdgcn_exp2f(__builtin_fmaf(s[t][3][r], C1, C2));
        l[t][r] += (p0 + p1) + (p2 + p3);
        uint2 pk;
        pk.x = f2bs2(p0, p1);
        pk.y = f2bs2(p2, p3);
        *reinterpret_cast<uint2*>(lp + (t * 16 + quad * 4 + r) * 72 + sto) = pk;
      }
    }
    __builtin_amdgcn_wave_barrier();
    short8 pa[2][2];
#pragma unroll
    for (int t = 0; t < 2; ++t) {
      const short* rp = lp + (t * 16 + col) * 72 + rdo;
      pa[t][0] = *reinterpret_cast<const short8*>(rp);
      pa[t][1] = *reinterpret_cast<const short8*>(rp + 32);
    }

    // PV: V-frags read once, shared by both subtiles
#pragma unroll
    for (int f = 0; f < 4; ++f) {
      const short* vr = vb_ + (f * 16 + col) * 72 + quad * 8;
      short8 v0 = *reinterpret_cast<const short8*>(vr);
      short8 v1 = *reinterpret_cast<const short8*>(vr + 32);
      o[0][f] = __builtin_amdgcn_mfma_f32_16x16x32_bf16(pa[0][0], v0, o[0][f], 0, 0, 0);
      o[0][f] = __builtin_amdgcn_mfma_f32_16x16x32_bf16(pa[0][1], v1, o[0][f], 0, 0, 0);
      o[1][f] = __builtin_amdgcn_mfma_f32_16x16x32_bf16(pa[1][0], v0, o[1][f], 0, 0, 0);
      o[1][f] = __builtin_amdgcn_mfma_f32_16x16x32_bf16(pa[1][1], v1, o[1][f], 0, 0, 0);
    }
    // no tail barrier: next iter's head barrier is the fence (dbuf)
  }

  // Denominator reduction + normalize + store
  int b = bh >> 3, h = bh & 7;
#pragma unroll
  for (int t = 0; t < 2; ++t) {
#pragma unroll
    for (int r = 0; r < 4; ++r) {
      float tt = l[t][r];
      tt += __shfl_xor(tt, 1);
      tt += __shfl_xor(tt, 2);
      tt += __shfl_xor(tt, 4);
      tt += __shfl_xor(tt, 8);
      float inv = __builtin_amdgcn_rcpf(tt);
      int row = q0 + t * 16 + quad * 4 + r;
      bf16* op = ao + ((size_t)b * S_ + row) * E_ + h * DK_;
      op[col]      = __float2bfloat16(o[t][0][r] * inv);
      op[16 + col] = __float2bfloat16(o[t][1][r] * inv);
      op[32 + col] = __float2bfloat16(o[t][2][r] * inv);
      op[48 + col] = __float2bfloat16(o[t][3][r] * inv);
    }
  }
}

// ---------------------------------------------------------------------------
// Kernel 4: out = attnout @ W^T + b  (M=8192, N=512, K=512), fp32 out.
// LDS-STAGED (fixes the R2-style per-lane 16B @1KB-stride fragmentation):
// coalesced 16B-chunk staging into stride-72 tiles, b128 fragment reads,
// reg prefetch. 64x64 block, 4 waves.
// ---------------------------------------------------------------------------
__global__ __launch_bounds__(256) void proj_kernel(
    const bf16* __restrict__ ao, const bf16* __restrict__ wb,
    const float* __restrict__ bias, float* __restrict__ out) {
  const int tid = threadIdx.x;
  const int wave = tid >> 6, lane = tid & 63;
  const int col = lane & 15, quad = lane >> 4;
  const int m0 = blockIdx.x * 64;
  const int n0 = blockIdx.y * 64;
  __shared__ short at[64 * 72];
  __shared__ short bt[64 * 72];

  const int srow = tid >> 3;
  const int soct = (tid & 7) * 8;
  const int sd0 = srow * 72 + soct;
  const int sd1 = (srow + 32) * 72 + soct;
  const bf16* ag0 = ao + (size_t)(m0 + srow) * E_ + (tid & 7) * 8;
  const bf16* ag1 = ao + (size_t)(m0 + srow + 32) * E_ + (tid & 7) * 8;
  const bf16* bg0 = wb + (size_t)(n0 + srow) * E_ + (tid & 7) * 8;
  const bf16* bg1 = wb + (size_t)(n0 + srow + 32) * E_ + (tid & 7) * 8;

  short8 ar0 = ld8(ag0), ar1 = ld8(ag1), br0 = ld8(bg0), br1 = ld8(bg1);

  f32x4 acc[4] = {{0.f,0.f,0.f,0.f},{0.f,0.f,0.f,0.f},{0.f,0.f,0.f,0.f},{0.f,0.f,0.f,0.f}};

  for (int k0 = 0; k0 < E_; k0 += 64) {
    *reinterpret_cast<short8*>(at + sd0) = ar0;
    *reinterpret_cast<short8*>(at + sd1) = ar1;
    *reinterpret_cast<short8*>(bt + sd0) = br0;
    *reinterpret_cast<short8*>(bt + sd1) = br1;
    __syncthreads();
    if (k0 + 64 < E_) {
      ar0 = ld8(ag0 + k0 + 64);
      ar1 = ld8(ag1 + k0 + 64);
      br0 = ld8(bg0 + k0 + 64);
      br1 = ld8(bg1 + k0 + 64);
    }
    const short* ap = at + (wave * 16 + col) * 72 + quad * 8;
    short8 a0 = *reinterpret_cast<const short8*>(ap);
    short8 a1 = *reinterpret_cast<const short8*>(ap + 32);
#pragma unroll
    for (int f = 0; f < 4; ++f) {
      const short* bp = bt + (f * 16 + col) * 72 + quad * 8;
      short8 b0 = *reinterpret_cast<const short8*>(bp);
      short8 b1 = *reinterpret_cast<const short8*>(bp + 32);
      acc[f] = __builtin_amdgcn_mfma_f32_16x16x32_bf16(a0, b0, acc[f], 0, 0, 0);
      acc[f] = __builtin_amdgcn_mfma_f32_16x16x32_bf16(a1, b1, acc[f], 0, 0, 0);
    }
    __syncthreads();
  }

#pragma unroll
  for (int f = 0; f < 4; ++f) {
    float bv = bias[n0 + f * 16 + col];
#pragma unroll
    for (int r = 0; r < 4; ++r) {
      int row = m0 + wave * 16 + quad * 4 + r;
      out[(size_t)row * E_ + n0 + f * 16 + col] = acc[f][r] + bv;
    }
  }
}

// ---------------------------------------------------------------------------
// ws layout (~25.7 MB):
//   [0)        g   bf16 [B,H,S,DK]   8388608 B
//   [8388608)  gT  bf16 [B,H,DK,S]   8388608 B
//   [16777216) ao  bf16 [B,S,E]      8388608 B
//   [25165824) wb  bf16 [E,E]         524288 B
// ---------------------------------------------------------------------------
extern "C" void kernel_launch(void* const* d_in, const int* in_sizes, int n_in,
                              void* d_out, int out_size, void* d_ws, size_t ws_size,
                              hipStream_t stream) {
  const float* x = (const float*)d_in[0];
  const float* theta = (const float*)d_in[1];
  const float* W = (const float*)d_in[2];
  const float* bias = (const float*)d_in[3];
  float* out = (float*)d_out;
  char* ws = (char*)d_ws;
  const size_t gsz = (size_t)B_ * H_ * S_ * DK_ * sizeof(bf16);  // 8388608
  bf16* g = (bf16*)ws;
  bf16* gT = (bf16*)(ws + gsz);
  bf16* ao = (bf16*)(ws + 2 * gsz);
  bf16* wb = (bf16*)(ws + 3 * gsz);

  prep_g_kernel<<<dim3(S_ / 64, B_ * H_), 256, 0, stream>>>(x, theta, g, gT);
  prep_w_kernel<<<dim3((E_ * E_) / (256 * 4)), 256, 0, stream>>>(W, wb);
  attn_kernel<<<dim3(S_ / 128, B_ * H_), 256, 0, stream>>>(g, gT, ao);
  proj_kernel<<<dim3((B_ * S_) / 64, E_ / 64), 256, 0, stream>>>(ao, wb, bias, out);
}

// Round 6
// 141.265 us; speedup vs baseline: 2.4725x; 1.0028x over previous
//
#include <hip/hip_runtime.h>
#include <hip/hip_bf16.h>
#include <math.h>

// Problem constants (from reference): B=4, S=2048, E=512, H=8, DK=64
#define B_ 4
#define S_ 2048
#define E_ 512
#define H_ 8
#define DK_ 64

typedef __attribute__((ext_vector_type(8))) short short8;    // 8x16b (4 VGPRs)
typedef __attribute__((ext_vector_type(4))) short short4_t;  // 4x16b (8 B)
typedef __attribute__((ext_vector_type(4))) float f32x4;     // MFMA C/D frag
typedef _Float16 half4 __attribute__((ext_vector_type(4)));  // 4 f16 (2 VGPRs)

using bf16 = __hip_bfloat16;

__device__ inline short8 ld8(const void* p) {
  return *reinterpret_cast<const short8*>(p);
}

static __device__ inline unsigned short f2bs(float f) {
  __hip_bfloat16 h = __float2bfloat16(f);
  return (unsigned short)__builtin_bit_cast(short, h);
}

// 8 fp32 -> 8 bf16 packed in a short8
static __device__ inline short8 cvt8(float4 a, float4 b) {
  short8 r;
  r[0] = f2bs(a.x); r[1] = f2bs(a.y); r[2] = f2bs(a.z); r[3] = f2bs(a.w);
  r[4] = f2bs(b.x); r[5] = f2bs(b.y); r[6] = f2bs(b.z); r[7] = f2bs(b.w);
  return r;
}

// ---------------------------------------------------------------------------
// Kernel 1: g[b][h][s][d] = cos(x[b][s][h*64+d]+theta[d]) in bf16 (QK path),
// gTh[b][h][d][s] in f16 (PV path; f16 has more mantissa than bf16 for |v|<=1).
// ---------------------------------------------------------------------------
__global__ __launch_bounds__(256) void prep_g_kernel(
    const float* __restrict__ x, const float* __restrict__ theta,
    bf16* __restrict__ g, _Float16* __restrict__ gTh) {
  int bh = blockIdx.y;
  int b = bh >> 3, h = bh & 7;
  int s0 = blockIdx.x * 64;
  __shared__ _Float16 tile[64][68];
  int tid = threadIdx.x;
  const float* xp = x + ((size_t)(b * S_ + s0)) * E_ + h * DK_;
  bf16* gp = g + ((size_t)bh * S_ + s0) * DK_;
#pragma unroll
  for (int it = 0; it < 16; ++it) {
    int idx = it * 256 + tid;
    int sr = idx >> 6, dc = idx & 63;
    float val = __cosf(xp[(size_t)sr * E_ + dc] + theta[dc]);
    gp[sr * DK_ + dc] = __float2bfloat16(val);
    tile[sr][dc] = (_Float16)val;
  }
  __syncthreads();
  _Float16* gTp = gTh + ((size_t)bh * DK_) * S_ + s0;
#pragma unroll
  for (int it = 0; it < 16; ++it) {
    int idx = it * 256 + tid;
    int dr = idx >> 6, sc = idx & 63;
    gTp[(size_t)dr * S_ + sc] = tile[sc][dr];
  }
}

// ---------------------------------------------------------------------------
// Kernel 2: flash attention, TRANSPOSED-SCORE form (P never touches LDS).
//
// S^T = K.Q^T via mfma_16x16x32_bf16 (A = K-frag from LDS tile, B = Q-frag
// held in regs; same physical loads as before, operands swapped). S^T C-layout
// gives lane P^T[key=quad*4+r][q=col] -- exactly the B-operand layout of
// mfma_f32_16x16x16f16 (k = quad*4+j). So P: exp2 regs -> f16 cvt -> PV
// B-frag directly. PV: O^T = V^T.P^T, A = V^T b64-frags from the d-major
// f16 V tile. No P round-trip, no shuffles, no wave_barriers.
//
// Softmax shift: p = e^(s/8 + 2); s/8 in [-8,8] provably => p in
// [e^-6, e^10]: no f16 denormals, no overflow (<= 22026 < 65504). O,l in
// fp32; the shift cancels at final normalization.
// R3 barrier structure (single buffer, 2 barriers/iter) -- dbuf regressed.
// ---------------------------------------------------------------------------
__global__ __launch_bounds__(256) void attn_kernel(
    const bf16* __restrict__ g, const _Float16* __restrict__ gTh,
    bf16* __restrict__ ao) {
  const int tid = threadIdx.x;
  const int wave = tid >> 6, lane = tid & 63;
  const int col = lane & 15, quad = lane >> 4;
  const int bh = blockIdx.y;
  const int q0 = blockIdx.x * 128 + wave * 32;
  const bf16* gp = g + (size_t)bh * S_ * DK_;
  const _Float16* gvp = gTh + (size_t)bh * DK_ * S_;

  __shared__ short kt[64 * 72];       // K tile bf16: row = local key
  __shared__ _Float16 vt[64 * 72];    // V tile f16: row = d, cols = local key

  // Q fragments (B-operand of S^T; physically identical to A-frag loads)
  short8 qa[2][2];
#pragma unroll
  for (int qc = 0; qc < 2; ++qc) {
    const bf16* qp = gp + (size_t)(q0 + qc * 16 + col) * DK_ + quad * 8;
    qa[qc][0] = ld8(qp);
    qa[qc][1] = ld8(qp + 32);
  }

  f32x4 o[2][4];   // O^T accum: [qc][dc], row=d=quad*4+r, col=q
#pragma unroll
  for (int qc = 0; qc < 2; ++qc)
#pragma unroll
    for (int dc = 0; dc < 4; ++dc) o[qc][dc] = f32x4{0.f, 0.f, 0.f, 0.f};
  float l[2] = {0.f, 0.f};

  const float C1 = 0.18033688011112042f;  // 0.125 * log2(e)
  const float C2 = 2.8853900817779268f;   // +2 * log2(e)

  // Staging: 512 16B-chunks per tile; thread handles chunks tid and tid+256.
  const int srow = tid >> 3;
  const int soct = (tid & 7) * 8;
  const int sd0 = srow * 72 + soct;
  const int sd1 = (srow + 32) * 72 + soct;
  const bf16* kg0 = gp + tid * 8;
  const bf16* kg1 = gp + (tid + 256) * 8;
  const _Float16* vg0 = gvp + (size_t)srow * S_ + (tid & 7) * 8;
  const _Float16* vg1 = gvp + (size_t)(srow + 32) * S_ + (tid & 7) * 8;

  short8 kr0 = ld8(kg0), kr1 = ld8(kg1), vr0 = ld8(vg0), vr1 = ld8(vg1);

  for (int kk = 0; kk < S_; kk += 64) {
    *reinterpret_cast<short8*>(kt + sd0) = kr0;
    *reinterpret_cast<short8*>(kt + sd1) = kr1;
    *reinterpret_cast<short8*>(vt + sd0) = vr0;
    *reinterpret_cast<short8*>(vt + sd1) = vr1;
    __syncthreads();

    // Prefetch next tile (overlaps compute)
    if (kk + 64 < S_) {
      kr0 = ld8(kg0 + (kk + 64) * 64);
      kr1 = ld8(kg1 + (kk + 64) * 64);
      vr0 = ld8(vg0 + kk + 64);
      vr1 = ld8(vg1 + kk + 64);
    }

    // K A-frags (shared across both q-chunks)
    short8 kf[4][2];
#pragma unroll
    for (int kc = 0; kc < 4; ++kc) {
      const short* kp = kt + (kc * 16 + col) * 72 + quad * 8;
      kf[kc][0] = *reinterpret_cast<const short8*>(kp);
      kf[kc][1] = *reinterpret_cast<const short8*>(kp + 32);
    }

    // S^T = K.Q^T : C row = key (quad*4+r), col = q
    f32x4 s[2][4];
#pragma unroll
    for (int qc = 0; qc < 2; ++qc)
#pragma unroll
      for (int kc = 0; kc < 4; ++kc) {
        f32x4 z{0.f, 0.f, 0.f, 0.f};
        z = __builtin_amdgcn_mfma_f32_16x16x32_bf16(kf[kc][0], qa[qc][0], z, 0, 0, 0);
        s[qc][kc] = __builtin_amdgcn_mfma_f32_16x16x32_bf16(kf[kc][1], qa[qc][1], z, 0, 0, 0);
      }

    // p = exp2(s*C1 + C2), accumulate l, convert to f16 PV B-frags in regs
    half4 pf[2][4];
#pragma unroll
    for (int qc = 0; qc < 2; ++qc) {
#pragma unroll
      for (int kc = 0; kc < 4; ++kc) {
        float p0 = __builtin_amdgcn_exp2f(__builtin_fmaf(s[qc][kc][0], C1, C2));
        float p1 = __builtin_amdgcn_exp2f(__builtin_fmaf(s[qc][kc][1], C1, C2));
        float p2 = __builtin_amdgcn_exp2f(__builtin_fmaf(s[qc][kc][2], C1, C2));
        float p3 = __builtin_amdgcn_exp2f(__builtin_fmaf(s[qc][kc][3], C1, C2));
        l[qc] += (p0 + p1) + (p2 + p3);
        half4 pk;
        pk[0] = (_Float16)p0; pk[1] = (_Float16)p1;
        pk[2] = (_Float16)p2; pk[3] = (_Float16)p3;
        pf[qc][kc] = pk;
      }
    }

    // PV: O^T += V^T.P^T  (16x16x16 f16; A = V^T b64-frags, B = P^T in regs)
#pragma unroll
    for (int dc = 0; dc < 4; ++dc) {
      half4 vf[4];
#pragma unroll
      for (int kc = 0; kc < 4; ++kc)
        vf[kc] = *reinterpret_cast<const half4*>(vt + (dc * 16 + col) * 72 + kc * 16 + quad * 4);
#pragma unroll
      for (int qc = 0; qc < 2; ++qc)
#pragma unroll
        for (int kc = 0; kc < 4; ++kc)
          o[qc][dc] = __builtin_amdgcn_mfma_f32_16x16x16f16(vf[kc], pf[qc][kc], o[qc][dc], 0, 0, 0);
    }
    __syncthreads();
  }

  // l lives distributed over quads (lane holds its quad's keys for q=col):
  // reduce across the 4 quads (xor 16, 32), then normalize and store.
  int b = bh >> 3, h = bh & 7;
#pragma unroll
  for (int qc = 0; qc < 2; ++qc) {
    float t = l[qc];
    t += __shfl_xor(t, 16);
    t += __shfl_xor(t, 32);
    float inv = __builtin_amdgcn_rcpf(t);
    int row = q0 + qc * 16 + col;
    bf16* op = ao + ((size_t)b * S_ + row) * E_ + h * DK_;
#pragma unroll
    for (int dc = 0; dc < 4; ++dc) {
      short4_t pk;
      pk.x = f2bs(o[qc][dc][0] * inv);
      pk.y = f2bs(o[qc][dc][1] * inv);
      pk.z = f2bs(o[qc][dc][2] * inv);
      pk.w = f2bs(o[qc][dc][3] * inv);
      *reinterpret_cast<short4_t*>(op + dc * 16 + quad * 4) = pk;
    }
  }
}

// ---------------------------------------------------------------------------
// Kernel 3: out = attnout @ W^T + b  (M=8192, N=512, K=512), fp32 out.
// LDS-staged; W is read fp32 and converted to bf16 DURING staging (prep_w
// kernel eliminated; W is 1 MB -> L2-resident across re-reads).
// ---------------------------------------------------------------------------
__global__ __launch_bounds__(256) void proj_kernel(
    const bf16* __restrict__ ao, const float* __restrict__ W,
    const float* __restrict__ bias, float* __restrict__ out) {
  const int tid = threadIdx.x;
  const int wave = tid >> 6, lane = tid & 63;
  const int col = lane & 15, quad = lane >> 4;
  const int m0 = blockIdx.x * 64;
  const int n0 = blockIdx.y * 64;
  __shared__ short at[64 * 72];
  __shared__ short bt[64 * 72];

  const int srow = tid >> 3;
  const int soct = (tid & 7) * 8;
  const int sd0 = srow * 72 + soct;
  const int sd1 = (srow + 32) * 72 + soct;
  const bf16* ag0 = ao + (size_t)(m0 + srow) * E_ + (tid & 7) * 8;
  const bf16* ag1 = ao + (size_t)(m0 + srow + 32) * E_ + (tid & 7) * 8;
  const float* wg0 = W + (size_t)(n0 + srow) * E_ + (tid & 7) * 8;
  const float* wg1 = W + (size_t)(n0 + srow + 32) * E_ + (tid & 7) * 8;

  short8 ar0 = ld8(ag0), ar1 = ld8(ag1);
  float4 w00 = *reinterpret_cast<const float4*>(wg0);
  float4 w01 = *reinterpret_cast<const float4*>(wg0 + 4);
  float4 w10 = *reinterpret_cast<const float4*>(wg1);
  float4 w11 = *reinterpret_cast<const float4*>(wg1 + 4);

  f32x4 acc[4] = {{0.f,0.f,0.f,0.f},{0.f,0.f,0.f,0.f},{0.f,0.f,0.f,0.f},{0.f,0.f,0.f,0.f}};

  for (int k0 = 0; k0 < E_; k0 += 64) {
    *reinterpret_cast<short8*>(at + sd0) = ar0;
    *reinterpret_cast<short8*>(at + sd1) = ar1;
    *reinterpret_cast<short8*>(bt + sd0) = cvt8(w00, w01);
    *reinterpret_cast<short8*>(bt + sd1) = cvt8(w10, w11);
    __syncthreads();
    if (k0 + 64 < E_) {
      ar0 = ld8(ag0 + k0 + 64);
      ar1 = ld8(ag1 + k0 + 64);
      w00 = *reinterpret_cast<const float4*>(wg0 + k0 + 64);
      w01 = *reinterpret_cast<const float4*>(wg0 + k0 + 68);
      w10 = *reinterpret_cast<const float4*>(wg1 + k0 + 64);
      w11 = *reinterpret_cast<const float4*>(wg1 + k0 + 68);
    }
    const short* ap = at + (wave * 16 + col) * 72 + quad * 8;
    short8 a0 = *reinterpret_cast<const short8*>(ap);
    short8 a1 = *reinterpret_cast<const short8*>(ap + 32);
#pragma unroll
    for (int f = 0; f < 4; ++f) {
      const short* bp = bt + (f * 16 + col) * 72 + quad * 8;
      short8 b0 = *reinterpret_cast<const short8*>(bp);
      short8 b1 = *reinterpret_cast<const short8*>(bp + 32);
      acc[f] = __builtin_amdgcn_mfma_f32_16x16x32_bf16(a0, b0, acc[f], 0, 0, 0);
      acc[f] = __builtin_amdgcn_mfma_f32_16x16x32_bf16(a1, b1, acc[f], 0, 0, 0);
    }
    __syncthreads();
  }

#pragma unroll
  for (int f = 0; f < 4; ++f) {
    float bv = bias[n0 + f * 16 + col];
#pragma unroll
    for (int r = 0; r < 4; ++r) {
      int row = m0 + wave * 16 + quad * 4 + r;
      out[(size_t)row * E_ + n0 + f * 16 + col] = acc[f][r] + bv;
    }
  }
}

// ---------------------------------------------------------------------------
// ws layout (~24 MB):
//   [0)        g    bf16 [B,H,S,DK]   8388608 B
//   [8388608)  gTh  f16  [B,H,DK,S]   8388608 B
//   [16777216) ao   bf16 [B,S,E]      8388608 B
// ---------------------------------------------------------------------------
extern "C" void kernel_launch(void* const* d_in, const int* in_sizes, int n_in,
                              void* d_out, int out_size, void* d_ws, size_t ws_size,
                              hipStream_t stream) {
  const float* x = (const float*)d_in[0];
  const float* theta = (const float*)d_in[1];
  const float* W = (const float*)d_in[2];
  const float* bias = (const float*)d_in[3];
  float* out = (float*)d_out;
  char* ws = (char*)d_ws;
  const size_t gsz = (size_t)B_ * H_ * S_ * DK_ * 2;  // 8388608
  bf16* g = (bf16*)ws;
  _Float16* gTh = (_Float16*)(ws + gsz);
  bf16* ao = (bf16*)(ws + 2 * gsz);

  prep_g_kernel<<<dim3(S_ / 64, B_ * H_), 256, 0, stream>>>(x, theta, g, gTh);
  attn_kernel<<<dim3(S_ / 128, B_ * H_), 256, 0, stream>>>(g, gTh, ao);
  proj_kernel<<<dim3((B_ * S_) / 64, E_ / 64), 256, 0, stream>>>(ao, W, bias, out);
}

// Round 7
// 137.082 us; speedup vs baseline: 2.5480x; 1.0305x over previous
//
#include <hip/hip_runtime.h>
#include <hip/hip_bf16.h>
#include <math.h>

// Problem constants (from reference): B=4, S=2048, E=512, H=8, DK=64
#define B_ 4
#define S_ 2048
#define E_ 512
#define H_ 8
#define DK_ 64

typedef __attribute__((ext_vector_type(8))) short short8;    // 8x16b (4 VGPRs)
typedef __attribute__((ext_vector_type(4))) float f32x4;     // MFMA C/D frag
typedef _Float16 half8 __attribute__((ext_vector_type(8)));  // 8 f16
typedef _Float16 half4 __attribute__((ext_vector_type(4)));  // 4 f16

__device__ inline short8 ld8(const void* p) {
  return *reinterpret_cast<const short8*>(p);
}

// 8 fp32 -> 8 f16 packed
static __device__ inline short8 cvt8h(float4 a, float4 b) {
  half8 r;
  r[0] = (_Float16)a.x; r[1] = (_Float16)a.y; r[2] = (_Float16)a.z; r[3] = (_Float16)a.w;
  r[4] = (_Float16)b.x; r[5] = (_Float16)b.y; r[6] = (_Float16)b.z; r[7] = (_Float16)b.w;
  return __builtin_bit_cast(short8, r);
}

// ---------------------------------------------------------------------------
// Kernel 1: g[b][h][s][d] = cos(x[b][s][h*64+d]+theta[d]) f16 (Q/K source),
// gTh[b][h][d][s] f16 (V-tile staging source). f16 everywhere: |cos|<=1, and
// f16's 10-bit mantissa beats bf16 for this range.
// ---------------------------------------------------------------------------
__global__ __launch_bounds__(256) void prep_g_kernel(
    const float* __restrict__ x, const float* __restrict__ theta,
    _Float16* __restrict__ g, _Float16* __restrict__ gTh) {
  int bh = blockIdx.y;
  int b = bh >> 3, h = bh & 7;
  int s0 = blockIdx.x * 64;
  __shared__ _Float16 tile[64][68];
  int tid = threadIdx.x;
  const float* xp = x + ((size_t)(b * S_ + s0)) * E_ + h * DK_;
  _Float16* gp = g + ((size_t)bh * S_ + s0) * DK_;
#pragma unroll
  for (int it = 0; it < 16; ++it) {
    int idx = it * 256 + tid;
    int sr = idx >> 6, dc = idx & 63;
    float val = __cosf(xp[(size_t)sr * E_ + dc] + theta[dc]);
    gp[sr * DK_ + dc] = (_Float16)val;
    tile[sr][dc] = (_Float16)val;
  }
  __syncthreads();
  _Float16* gTp = gTh + ((size_t)bh * DK_) * S_ + s0;
#pragma unroll
  for (int it = 0; it < 16; ++it) {
    int idx = it * 256 + tid;
    int dr = idx >> 6, sc = idx & 63;
    gTp[(size_t)dr * S_ + sc] = tile[sc][dr];
  }
}

// ---------------------------------------------------------------------------
// Kernel 2: flash attention, KEY-SPLIT waves (fixes R6's DS saturation: all
// 4 waves read the full 16 KB tile -> 4x LDS read amplification).
//
// Block = 64 q rows shared by ALL 4 waves (Q-frags in regs, staged once).
// Wave w owns keys [w*16, w*16+16) of every 64-key tile -> block reads each
// tile exactly once. O, l are per-wave partials over disjoint keys (legal:
// constant-shift softmax = plain sums), combined in a one-time LDS reduction.
//
// Q pre-scaled by 0.125*log2(e) at frag load -> p = exp2(s_raw') directly,
// no per-score FMA. p in [2^-11.5, 2^11.5]: f16-normal, no overflow; the
// missing shift cancels at normalization.
//
// S^T = K.Q'^T (mfma 16x16x32 f16, A=K-frag, B=Q-frag); S^T C-layout gives
// lane P^T[key=quad*4+r][q=col] = B-operand of 16x16x16 f16 exactly; PV is
// O^T += V^T.P^T with V^T A-frags (b64) from the d-major V tile.
// ---------------------------------------------------------------------------
__global__ __launch_bounds__(256, 3) void attn_kernel(
    const _Float16* __restrict__ g, const _Float16* __restrict__ gTh,
    _Float16* __restrict__ ao) {
  const int tid = threadIdx.x;
  const int wave = tid >> 6, lane = tid & 63;
  const int col = lane & 15, quad = lane >> 4;
  const int bh = blockIdx.y;
  const int q0 = blockIdx.x * 64;
  const _Float16* gp = g + (size_t)bh * S_ * DK_;
  const _Float16* gvp = gTh + (size_t)bh * DK_ * S_;

  __shared__ short smem[2 * 64 * 72];  // kt | vt ; reused for Q-stage + reductions
  short* kt = smem;
  short* vt = smem + 64 * 72;

  const int srow = tid >> 3;
  const int soct = (tid & 7) * 8;
  const int sd0 = srow * 72 + soct;
  const int sd1 = (srow + 32) * 72 + soct;
  const _Float16* kg0 = gp + tid * 8;
  const _Float16* kg1 = gp + (tid + 256) * 8;
  const _Float16* vg0 = gvp + (size_t)srow * S_ + (tid & 7) * 8;
  const _Float16* vg1 = gvp + (size_t)(srow + 32) * S_ + (tid & 7) * 8;

  // Initial K/V prefetch (kk=0) — independent of the Q-stage below
  short8 kr0 = ld8(kg0), kr1 = ld8(kg1), vr0 = ld8(vg0), vr1 = ld8(vg1);

  // ---- Q stage: rows q0..q0+63 through LDS (coalesced), frags to regs ----
  *reinterpret_cast<short8*>(kt + sd0) = ld8(gp + (size_t)q0 * DK_ + tid * 8);
  *reinterpret_cast<short8*>(kt + sd1) = ld8(gp + (size_t)q0 * DK_ + (tid + 256) * 8);
  __syncthreads();
  const _Float16 hC1 = (_Float16)0.18033688011112042f;  // 0.125*log2(e)
  half8 qa[4][2];
#pragma unroll
  for (int qc = 0; qc < 4; ++qc) {
    const short* qp = kt + (qc * 16 + col) * 72 + quad * 8;
    qa[qc][0] = *reinterpret_cast<const half8*>(qp) * hC1;
    qa[qc][1] = *reinterpret_cast<const half8*>(qp + 32) * hC1;
  }
  __syncthreads();  // Q reads done before K staging overwrites kt

  f32x4 o[4][4];  // O^T partial (this wave's keys): [qc][dc]
#pragma unroll
  for (int qc = 0; qc < 4; ++qc)
#pragma unroll
    for (int dc = 0; dc < 4; ++dc) o[qc][dc] = f32x4{0.f, 0.f, 0.f, 0.f};
  float l[4] = {0.f, 0.f, 0.f, 0.f};

  for (int kk = 0; kk < S_; kk += 64) {
    *reinterpret_cast<short8*>(kt + sd0) = kr0;
    *reinterpret_cast<short8*>(kt + sd1) = kr1;
    *reinterpret_cast<short8*>(vt + sd0) = vr0;
    *reinterpret_cast<short8*>(vt + sd1) = vr1;
    __syncthreads();

    if (kk + 64 < S_) {
      kr0 = ld8(kg0 + (kk + 64) * 64);
      kr1 = ld8(kg1 + (kk + 64) * 64);
      vr0 = ld8(vg0 + kk + 64);
      vr1 = ld8(vg1 + kk + 64);
    }

    // This wave's K-frags only (16 keys): 2 b128
    const short* kp = kt + (wave * 16 + col) * 72 + quad * 8;
    half8 kf0 = *reinterpret_cast<const half8*>(kp);
    half8 kf1 = *reinterpret_cast<const half8*>(kp + 32);

    half4 pf[4];
#pragma unroll
    for (int qc = 0; qc < 4; ++qc) {
      f32x4 z{0.f, 0.f, 0.f, 0.f};
      z = __builtin_amdgcn_mfma_f32_16x16x32_f16(kf0, qa[qc][0], z, 0, 0, 0);
      z = __builtin_amdgcn_mfma_f32_16x16x32_f16(kf1, qa[qc][1], z, 0, 0, 0);
      float p0 = __builtin_amdgcn_exp2f(z[0]);
      float p1 = __builtin_amdgcn_exp2f(z[1]);
      float p2 = __builtin_amdgcn_exp2f(z[2]);
      float p3 = __builtin_amdgcn_exp2f(z[3]);
      l[qc] += (p0 + p1) + (p2 + p3);
      half4 pk;
      pk[0] = (_Float16)p0; pk[1] = (_Float16)p1;
      pk[2] = (_Float16)p2; pk[3] = (_Float16)p3;
      pf[qc] = pk;
    }

    // PV over this wave's 16 keys: V-frags 4 b64
#pragma unroll
    for (int dc = 0; dc < 4; ++dc) {
      half4 vf = *reinterpret_cast<const half4*>(
          vt + (dc * 16 + col) * 72 + wave * 16 + quad * 4);
#pragma unroll
      for (int qc = 0; qc < 4; ++qc)
        o[qc][dc] = __builtin_amdgcn_mfma_f32_16x16x16f16(vf, pf[qc], o[qc][dc], 0, 0, 0);
    }
    __syncthreads();
  }

  // ---- Reductions across waves (disjoint key slices) ----
  // l: quad-reduce within wave, then cross-wave via LDS.
#pragma unroll
  for (int qc = 0; qc < 4; ++qc) {
    float t = l[qc];
    t += __shfl_xor(t, 16);
    t += __shfl_xor(t, 32);
    l[qc] = t;
  }
  float* red = (float*)smem;
  if (quad == 0) {
#pragma unroll
    for (int qc = 0; qc < 4; ++qc) red[(wave * 4 + qc) * 16 + col] = l[qc];
  }
  __syncthreads();
  float ltot = 0.f;
#pragma unroll
  for (int w2 = 0; w2 < 4; ++w2) ltot += red[(w2 * 4 + wave) * 16 + col];
  float inv = __builtin_amdgcn_rcpf(ltot);  // denominator for qc == wave

  // O: 4 rounds; wave w owns qc=w (16 q rows). 16 KB scratch per round.
  int b = bh >> 3, h = bh & 7;
  float* ored = (float*)smem;
#pragma unroll
  for (int qc = 0; qc < 4; ++qc) {
    __syncthreads();  // previous round's reads (or l-reduction) complete
#pragma unroll
    for (int dc = 0; dc < 4; ++dc)
      *reinterpret_cast<f32x4*>(ored + wave * 1024 + lane * 16 + dc * 4) = o[qc][dc];
    __syncthreads();
    if (wave == qc) {
      _Float16* op = ao + ((size_t)b * S_ + (q0 + qc * 16 + col)) * E_ + h * DK_;
#pragma unroll
      for (int dc = 0; dc < 4; ++dc) {
        f32x4 acc = *reinterpret_cast<const f32x4*>(ored + lane * 16 + dc * 4);
#pragma unroll
        for (int w2 = 1; w2 < 4; ++w2)
          acc = acc + *reinterpret_cast<const f32x4*>(ored + w2 * 1024 + lane * 16 + dc * 4);
        half4 pk;
        pk[0] = (_Float16)(acc[0] * inv);
        pk[1] = (_Float16)(acc[1] * inv);
        pk[2] = (_Float16)(acc[2] * inv);
        pk[3] = (_Float16)(acc[3] * inv);
        *reinterpret_cast<half4*>(op + dc * 16 + quad * 4) = pk;
      }
    }
  }
}

// ---------------------------------------------------------------------------
// Kernel 3: out = attnout @ W^T + b  (M=8192, N=512, K=512), fp32 out.
// LDS-staged, BK=128 (4 iters, half the barriers of R6's BK=64). W converted
// fp32->f16 during staging. f16 MFMA (x32).
// ---------------------------------------------------------------------------
__global__ __launch_bounds__(256) void proj_kernel(
    const _Float16* __restrict__ ao, const float* __restrict__ W,
    const float* __restrict__ bias, float* __restrict__ out) {
  const int tid = threadIdx.x;
  const int wave = tid >> 6, lane = tid & 63;
  const int col = lane & 15, quad = lane >> 4;
  const int m0 = blockIdx.x * 64;
  const int n0 = blockIdx.y * 64;
  __shared__ short at[64 * 136];  // 64 rows x 128 k, stride 136 (68w = 4 mod 32)
  __shared__ short bt[64 * 136];

  const int srw = tid >> 4;        // 0..15 (+16 per chunk-it)
  const int soff = (tid & 15) * 8; // 0..120

  short8 ap_[4];
  float4 wp_[4][2];
#pragma unroll
  for (int it = 0; it < 4; ++it) {
    int row = it * 16 + srw;
    ap_[it] = ld8(ao + (size_t)(m0 + row) * E_ + soff);
    wp_[it][0] = *reinterpret_cast<const float4*>(W + (size_t)(n0 + row) * E_ + soff);
    wp_[it][1] = *reinterpret_cast<const float4*>(W + (size_t)(n0 + row) * E_ + soff + 4);
  }

  f32x4 acc[4] = {{0.f,0.f,0.f,0.f},{0.f,0.f,0.f,0.f},{0.f,0.f,0.f,0.f},{0.f,0.f,0.f,0.f}};

  for (int k0 = 0; k0 < E_; k0 += 128) {
#pragma unroll
    for (int it = 0; it < 4; ++it) {
      int row = it * 16 + srw;
      *reinterpret_cast<short8*>(at + row * 136 + soff) = ap_[it];
      *reinterpret_cast<short8*>(bt + row * 136 + soff) = cvt8h(wp_[it][0], wp_[it][1]);
    }
    __syncthreads();
    if (k0 + 128 < E_) {
#pragma unroll
      for (int it = 0; it < 4; ++it) {
        int row = it * 16 + srw;
        ap_[it] = ld8(ao + (size_t)(m0 + row) * E_ + k0 + 128 + soff);
        wp_[it][0] = *reinterpret_cast<const float4*>(W + (size_t)(n0 + row) * E_ + k0 + 128 + soff);
        wp_[it][1] = *reinterpret_cast<const float4*>(W + (size_t)(n0 + row) * E_ + k0 + 132 + soff);
      }
    }
#pragma unroll
    for (int ks = 0; ks < 4; ++ks) {
      const short* ap = at + (wave * 16 + col) * 136 + ks * 32 + quad * 8;
      half8 a = *reinterpret_cast<const half8*>(ap);
#pragma unroll
      for (int f = 0; f < 4; ++f) {
        const short* bp = bt + (f * 16 + col) * 136 + ks * 32 + quad * 8;
        half8 bb = *reinterpret_cast<const half8*>(bp);
        acc[f] = __builtin_amdgcn_mfma_f32_16x16x32_f16(a, bb, acc[f], 0, 0, 0);
      }
    }
    __syncthreads();
  }

#pragma unroll
  for (int f = 0; f < 4; ++f) {
    float bv = bias[n0 + f * 16 + col];
#pragma unroll
    for (int r = 0; r < 4; ++r) {
      int row = m0 + wave * 16 + quad * 4 + r;
      out[(size_t)row * E_ + n0 + f * 16 + col] = acc[f][r] + bv;
    }
  }
}

// ---------------------------------------------------------------------------
// ws layout (~25 MB):
//   [0)        g    f16 [B,H,S,DK]   8388608 B
//   [8388608)  gTh  f16 [B,H,DK,S]   8388608 B
//   [16777216) ao   f16 [B,S,E]      8388608 B
// ---------------------------------------------------------------------------
extern "C" void kernel_launch(void* const* d_in, const int* in_sizes, int n_in,
                              void* d_out, int out_size, void* d_ws, size_t ws_size,
                              hipStream_t stream) {
  const float* x = (const float*)d_in[0];
  const float* theta = (const float*)d_in[1];
  const float* W = (const float*)d_in[2];
  const float* bias = (const float*)d_in[3];
  float* out = (float*)d_out;
  char* ws = (char*)d_ws;
  const size_t gsz = (size_t)B_ * H_ * S_ * DK_ * 2;  // 8388608
  _Float16* g = (_Float16*)ws;
  _Float16* gTh = (_Float16*)(ws + gsz);
  _Float16* ao = (_Float16*)(ws + 2 * gsz);

  prep_g_kernel<<<dim3(S_ / 64, B_ * H_), 256, 0, stream>>>(x, theta, g, gTh);
  attn_kernel<<<dim3(S_ / 64, B_ * H_), 256, 0, stream>>>(g, gTh, ao);
  proj_kernel<<<dim3((B_ * S_) / 64, E_ / 64), 256, 0, stream>>>(ao, W, bias, out);
}

// Round 9
// 128.954 us; speedup vs baseline: 2.7086x; 1.0630x over previous
//
#include <hip/hip_runtime.h>
#include <hip/hip_bf16.h>
#include <math.h>

// Problem constants (from reference): B=4, S=2048, E=512, H=8, DK=64
#define B_ 4
#define S_ 2048
#define E_ 512
#define H_ 8
#define DK_ 64

typedef __attribute__((ext_vector_type(8))) short short8;    // 8x16b (4 VGPRs)
typedef __attribute__((ext_vector_type(4))) float f32x4;     // MFMA C/D frag
typedef _Float16 half8 __attribute__((ext_vector_type(8)));  // 8 f16
typedef _Float16 half4 __attribute__((ext_vector_type(4)));  // 4 f16
typedef __fp16 fp16x2 __attribute__((ext_vector_type(2)));   // cvt_pkrtz result
typedef unsigned uint4v __attribute__((ext_vector_type(4)));

__device__ inline short8 ld8(const void* p) {
  return *reinterpret_cast<const short8*>(p);
}
__device__ inline half8 ld8h(const void* p) {
  return *reinterpret_cast<const half8*>(p);
}

static __device__ inline unsigned pk2(float a, float b) {
  fp16x2 h = __builtin_amdgcn_cvt_pkrtz(a, b);  // v_cvt_pkrtz_f16_f32
  return __builtin_bit_cast(unsigned, h);
}
static __device__ inline half8 pack8(float p0, float p1, float p2, float p3,
                                     float p4, float p5, float p6, float p7) {
  uint4v u;
  u[0] = pk2(p0, p1); u[1] = pk2(p2, p3);
  u[2] = pk2(p4, p5); u[3] = pk2(p6, p7);
  return __builtin_bit_cast(half8, u);
}

// ---------------------------------------------------------------------------
// Fragment-order layouts:
// kA[bh] : per 32-key group G (64 groups), 4 chunks of 1 KB: (g,h), g=key-sub,
//   h=DK-half. Chunk lane ell=(quad,col): 16B = K[32G + (col>>2)*8 + g*4 +
//   (col&3)][h*32 + quad*8 .. +8].  This is the 16x16x32 A/B-operand layout
//   with the key PERMUTATION that makes the two QK C-tiles (rows quad*4+r)
//   concatenate into the K=32 B-operand (k=quad*8+(g*4+r)) for PV.
// vA[bh] : per G, 4 chunks (dc): lane 16B = V[32G + quad*8 + j][dc*16+col],
//   j=0..7 -> the 16x16x32 A-operand for V^T (m=d, k=key), key order matching
//   pf's j = g*4+r mapping.
// A wave loads its frags as ONE coalesced 1KB dwordx4 per chunk. No LDS.
// ---------------------------------------------------------------------------

// ---------------------------------------------------------------------------
// Kernel 1: cos(x+theta) -> kA (frag order, serves Q and K) + vA (frag order).
// ---------------------------------------------------------------------------
__global__ __launch_bounds__(256) void prep_g_kernel(
    const float* __restrict__ x, const float* __restrict__ theta,
    _Float16* __restrict__ kA, _Float16* __restrict__ vA) {
  const int bh = blockIdx.y;
  const int b = bh >> 3, h = bh & 7;
  const int s0 = blockIdx.x * 64;
  const int tid = threadIdx.x;
  const int wave = tid >> 6, lane = tid & 63;
  const int col = lane & 15, quad = lane >> 4;
  __shared__ _Float16 tile[64 * 72];

  const float* xp = x + ((size_t)(b * S_ + s0)) * E_ + h * DK_;
#pragma unroll
  for (int it = 0; it < 16; ++it) {
    int idx = it * 256 + tid;
    int sr = idx >> 6, dc = idx & 63;
    tile[sr * 72 + dc] = (_Float16)__cosf(xp[(size_t)sr * E_ + dc] + theta[dc]);
  }
  __syncthreads();

  _Float16* kb = kA + (size_t)bh * (S_ * DK_);
  _Float16* vb = vA + (size_t)bh * (S_ * DK_);
  const int Gbase = s0 >> 5;
  // kA: 8 chunks (2 Gl x 2 g x 2 hh); wave handles chunk wave + it2*4
#pragma unroll
  for (int it2 = 0; it2 < 2; ++it2) {
    int c = wave + it2 * 4;
    int Gl = c >> 2, g = (c >> 1) & 1, hh = c & 1;
    int ploc = Gl * 32 + ((col >> 2) << 3) + g * 4 + (col & 3);
    half8 v = ld8h(tile + ploc * 72 + hh * 32 + quad * 8);
    *reinterpret_cast<half8*>(
        kb + ((size_t)(Gbase + Gl) * 2048 + (g * 2 + hh) * 512 + lane * 8)) = v;
  }
  // vA: 8 chunks (2 Gl x 4 dcc); transposed gather from tile
#pragma unroll
  for (int it2 = 0; it2 < 2; ++it2) {
    int c = wave + it2 * 4;
    int Gl = c >> 2, dcc = c & 3;
    half8 v;
#pragma unroll
    for (int j = 0; j < 8; ++j)
      v[j] = tile[(Gl * 32 + quad * 8 + j) * 72 + dcc * 16 + col];
    *reinterpret_cast<half8*>(
        vb + ((size_t)(Gbase + Gl) * 2048 + dcc * 512 + lane * 8)) = v;
  }
}

// ---------------------------------------------------------------------------
// Kernel 2: W (fp32) -> f16 (once; proj previously re-converted W 128x)
// ---------------------------------------------------------------------------
__global__ void prep_w_kernel(const float* __restrict__ W, _Float16* __restrict__ wb) {
  int i = (blockIdx.x * 256 + threadIdx.x) * 8;
  float4 a = *reinterpret_cast<const float4*>(W + i);
  float4 c = *reinterpret_cast<const float4*>(W + i + 4);
  half8 v;
  v[0]=(_Float16)a.x; v[1]=(_Float16)a.y; v[2]=(_Float16)a.z; v[3]=(_Float16)a.w;
  v[4]=(_Float16)c.x; v[5]=(_Float16)c.y; v[6]=(_Float16)c.z; v[7]=(_Float16)c.w;
  *reinterpret_cast<half8*>(wb + i) = v;
}

// ---------------------------------------------------------------------------
// Kernel 3: attention — BARRIER-FREE, LDS-FREE K-loop.
// Block = 64 q (frags from kA, scaled by 0.125*log2e at load; q columns carry
// the kA permutation, undone at the final store). Wave w owns keys
// [w*512,(w+1)*512), 16 iters x 32 keys:
//   8 coalesced global b128 loads (4 K chunks, 4 V chunks)
//   QK: 16 mfma 16x16x32 f16 (S^T = K.Q'^T); exp2 -> pf (K=32 B-operand via
//   the kA key permutation); PV: 16 mfma 16x16x32 f16 (O^T += V^T.P^T).
// No __syncthreads / LDS until the one-time cross-wave reduction (R7 scheme).
// p = exp2(s_raw/8 * log2e) in [e-8, e8]: f16-normal; shift-free softmax.
// ---------------------------------------------------------------------------
__global__ __launch_bounds__(256, 3) void attn_kernel(
    const _Float16* __restrict__ kA, const _Float16* __restrict__ vA,
    _Float16* __restrict__ ao) {
  const int tid = threadIdx.x;
  const int wave = tid >> 6, lane = tid & 63;
  const int col = lane & 15, quad = lane >> 4;
  const int bh = blockIdx.y;
  const int q0 = blockIdx.x * 64;
  const _Float16* kb = kA + (size_t)bh * (S_ * DK_);
  const _Float16* vb = vA + (size_t)bh * (S_ * DK_);

  // Q frags: qc=(Gq,g): chunk ((q0>>5)+Gq, g, h), scaled by C1
  const _Float16 hC1 = (_Float16)0.18033688011112042f;  // 0.125*log2(e)
  half8 qa[4][2];
#pragma unroll
  for (int qc = 0; qc < 4; ++qc)
#pragma unroll
    for (int hh = 0; hh < 2; ++hh)
      qa[qc][hh] = ld8h(kb + (size_t)((q0 >> 5) + (qc >> 1)) * 2048 +
                        ((qc & 1) * 2 + hh) * 512 + lane * 8) * hC1;

  f32x4 o[4][4];
#pragma unroll
  for (int qc = 0; qc < 4; ++qc)
#pragma unroll
    for (int dc = 0; dc < 4; ++dc) o[qc][dc] = f32x4{0.f, 0.f, 0.f, 0.f};
  float l[4] = {0.f, 0.f, 0.f, 0.f};

  const _Float16* kw = kb + (size_t)wave * 16 * 2048 + lane * 8;
  const _Float16* vw = vb + (size_t)wave * 16 * 2048 + lane * 8;

  for (int it = 0; it < 16; ++it) {
    const _Float16* kit = kw + it * 2048;
    const _Float16* vit = vw + it * 2048;
    half8 kf00 = ld8h(kit);
    half8 kf01 = ld8h(kit + 512);
    half8 kf10 = ld8h(kit + 1024);
    half8 kf11 = ld8h(kit + 1536);
    half8 vf0 = ld8h(vit);
    half8 vf1 = ld8h(vit + 512);
    half8 vf2 = ld8h(vit + 1024);
    half8 vf3 = ld8h(vit + 1536);

    half8 pf[4];
#pragma unroll
    for (int qc = 0; qc < 4; ++qc) {
      f32x4 z0{0.f, 0.f, 0.f, 0.f}, z1{0.f, 0.f, 0.f, 0.f};
      z0 = __builtin_amdgcn_mfma_f32_16x16x32_f16(kf00, qa[qc][0], z0, 0, 0, 0);
      z0 = __builtin_amdgcn_mfma_f32_16x16x32_f16(kf01, qa[qc][1], z0, 0, 0, 0);
      z1 = __builtin_amdgcn_mfma_f32_16x16x32_f16(kf10, qa[qc][0], z1, 0, 0, 0);
      z1 = __builtin_amdgcn_mfma_f32_16x16x32_f16(kf11, qa[qc][1], z1, 0, 0, 0);
      float p0 = __builtin_amdgcn_exp2f(z0[0]);
      float p1 = __builtin_amdgcn_exp2f(z0[1]);
      float p2 = __builtin_amdgcn_exp2f(z0[2]);
      float p3 = __builtin_amdgcn_exp2f(z0[3]);
      float p4 = __builtin_amdgcn_exp2f(z1[0]);
      float p5 = __builtin_amdgcn_exp2f(z1[1]);
      float p6 = __builtin_amdgcn_exp2f(z1[2]);
      float p7 = __builtin_amdgcn_exp2f(z1[3]);
      l[qc] += ((p0 + p1) + (p2 + p3)) + ((p4 + p5) + (p6 + p7));
      pf[qc] = pack8(p0, p1, p2, p3, p4, p5, p6, p7);
    }
#pragma unroll
    for (int qc = 0; qc < 4; ++qc) {
      o[qc][0] = __builtin_amdgcn_mfma_f32_16x16x32_f16(vf0, pf[qc], o[qc][0], 0, 0, 0);
      o[qc][1] = __builtin_amdgcn_mfma_f32_16x16x32_f16(vf1, pf[qc], o[qc][1], 0, 0, 0);
      o[qc][2] = __builtin_amdgcn_mfma_f32_16x16x32_f16(vf2, pf[qc], o[qc][2], 0, 0, 0);
      o[qc][3] = __builtin_amdgcn_mfma_f32_16x16x32_f16(vf3, pf[qc], o[qc][3], 0, 0, 0);
    }
  }

  // ---- one-time cross-wave reduction (R7 scheme) ----
  __shared__ float reds[4096];  // 16 KB
#pragma unroll
  for (int qc = 0; qc < 4; ++qc) {
    float t = l[qc];
    t += __shfl_xor(t, 16);
    t += __shfl_xor(t, 32);
    l[qc] = t;
  }
  if (quad == 0) {
#pragma unroll
    for (int qc = 0; qc < 4; ++qc) reds[(wave * 4 + qc) * 16 + col] = l[qc];
  }
  __syncthreads();
  float ltot = 0.f;
#pragma unroll
  for (int w2 = 0; w2 < 4; ++w2) ltot += reds[(w2 * 4 + wave) * 16 + col];
  float inv = __builtin_amdgcn_rcpf(ltot);  // denominator for qc == wave

  const int b = bh >> 3, h = bh & 7;
  // store row carries the kA q-permutation: qc=(Gq,g), col -> q
  const int qrow = q0 + ((wave >> 1) << 5) + ((col >> 2) << 3) + (wave & 1) * 4 + (col & 3);
  _Float16* op = ao + ((size_t)b * S_ + qrow) * E_ + h * DK_;
#pragma unroll
  for (int qc = 0; qc < 4; ++qc) {
    __syncthreads();
#pragma unroll
    for (int dc = 0; dc < 4; ++dc)
      *reinterpret_cast<f32x4*>(reds + wave * 1024 + lane * 16 + dc * 4) = o[qc][dc];
    __syncthreads();
    if (wave == qc) {
#pragma unroll
      for (int dc = 0; dc < 4; ++dc) {
        f32x4 acc = *reinterpret_cast<const f32x4*>(reds + lane * 16 + dc * 4);
#pragma unroll
        for (int w2 = 1; w2 < 4; ++w2)
          acc = acc + *reinterpret_cast<const f32x4*>(reds + w2 * 1024 + lane * 16 + dc * 4);
        half4 pk4;
        pk4[0] = (_Float16)(acc[0] * inv);
        pk4[1] = (_Float16)(acc[1] * inv);
        pk4[2] = (_Float16)(acc[2] * inv);
        pk4[3] = (_Float16)(acc[3] * inv);
        *reinterpret_cast<half4*>(op + dc * 16 + quad * 4) = pk4;
      }
    }
  }
}

// ---------------------------------------------------------------------------
// Kernel 4: out = attnout @ W^T + b  (M=8192, N=512, K=512), fp32 out.
// R7 structure (LDS-staged, BK=128) but reads pre-converted wb f16.
// ---------------------------------------------------------------------------
__global__ __launch_bounds__(256) void proj_kernel(
    const _Float16* __restrict__ ao, const _Float16* __restrict__ wb,
    const float* __restrict__ bias, float* __restrict__ out) {
  const int tid = threadIdx.x;
  const int wave = tid >> 6, lane = tid & 63;
  const int col = lane & 15, quad = lane >> 4;
  const int m0 = blockIdx.x * 64;
  const int n0 = blockIdx.y * 64;
  __shared__ short at[64 * 136];
  __shared__ short bt[64 * 136];

  const int srw = tid >> 4;        // 0..15
  const int soff = (tid & 15) * 8; // 0..120

  short8 ap_[4], wp_[4];
#pragma unroll
  for (int it = 0; it < 4; ++it) {
    int row = it * 16 + srw;
    ap_[it] = ld8(ao + (size_t)(m0 + row) * E_ + soff);
    wp_[it] = ld8(wb + (size_t)(n0 + row) * E_ + soff);
  }

  f32x4 acc[4] = {{0.f,0.f,0.f,0.f},{0.f,0.f,0.f,0.f},{0.f,0.f,0.f,0.f},{0.f,0.f,0.f,0.f}};

  for (int k0 = 0; k0 < E_; k0 += 128) {
#pragma unroll
    for (int it = 0; it < 4; ++it) {
      int row = it * 16 + srw;
      *reinterpret_cast<short8*>(at + row * 136 + soff) = ap_[it];
      *reinterpret_cast<short8*>(bt + row * 136 + soff) = wp_[it];
    }
    __syncthreads();
    if (k0 + 128 < E_) {
#pragma unroll
      for (int it = 0; it < 4; ++it) {
        int row = it * 16 + srw;
        ap_[it] = ld8(ao + (size_t)(m0 + row) * E_ + k0 + 128 + soff);
        wp_[it] = ld8(wb + (size_t)(n0 + row) * E_ + k0 + 128 + soff);
      }
    }
#pragma unroll
    for (int ks = 0; ks < 4; ++ks) {
      half8 a = *reinterpret_cast<const half8*>(at + (wave * 16 + col) * 136 + ks * 32 + quad * 8);
#pragma unroll
      for (int f = 0; f < 4; ++f) {
        half8 bb = *reinterpret_cast<const half8*>(bt + (f * 16 + col) * 136 + ks * 32 + quad * 8);
        acc[f] = __builtin_amdgcn_mfma_f32_16x16x32_f16(a, bb, acc[f], 0, 0, 0);
      }
    }
    __syncthreads();
  }

#pragma unroll
  for (int f = 0; f < 4; ++f) {
    float bv = bias[n0 + f * 16 + col];
#pragma unroll
    for (int r = 0; r < 4; ++r) {
      int row = m0 + wave * 16 + quad * 4 + r;
      out[(size_t)row * E_ + n0 + f * 16 + col] = acc[f][r] + bv;
    }
  }
}

// ---------------------------------------------------------------------------
// ws layout (~25.1 MB):
//   [0)        kA  f16 frag-order [B*H][64G][4][512]   8388608 B
//   [8388608)  vA  f16 frag-order                      8388608 B
//   [16777216) ao  f16 [B,S,E]                         8388608 B
//   [25165824) wb  f16 [E,E]                            524288 B
// ---------------------------------------------------------------------------
extern "C" void kernel_launch(void* const* d_in, const int* in_sizes, int n_in,
                              void* d_out, int out_size, void* d_ws, size_t ws_size,
                              hipStream_t stream) {
  const float* x = (const float*)d_in[0];
  const float* theta = (const float*)d_in[1];
  const float* W = (const float*)d_in[2];
  const float* bias = (const float*)d_in[3];
  float* out = (float*)d_out;
  char* ws = (char*)d_ws;
  const size_t gsz = (size_t)B_ * H_ * S_ * DK_ * 2;  // 8388608
  _Float16* kA = (_Float16*)ws;
  _Float16* vA = (_Float16*)(ws + gsz);
  _Float16* ao = (_Float16*)(ws + 2 * gsz);
  _Float16* wb = (_Float16*)(ws + 3 * gsz);

  prep_g_kernel<<<dim3(S_ / 64, B_ * H_), 256, 0, stream>>>(x, theta, kA, vA);
  prep_w_kernel<<<dim3((E_ * E_) / (256 * 8)), 256, 0, stream>>>(W, wb);
  attn_kernel<<<dim3(S_ / 64, B_ * H_), 256, 0, stream>>>(kA, vA, ao);
  proj_kernel<<<dim3((B_ * S_) / 64, E_ / 64), 256, 0, stream>>>(ao, wb, bias, out);
}